// Round 7
// baseline (243.281 us; speedup 1.0000x reference)
//
#include <hip/hip_runtime.h>
#include <math.h>

#define BATCH 8
#define TENC 2048
#define TDEC 512
#define DIM 1024
#define NEG_BIG 1e20f

typedef __attribute__((ext_vector_type(8))) short short8;
typedef __attribute__((ext_vector_type(4))) float f32x4;
typedef unsigned short ushort_t;

// ---- fp32 -> bf16 helpers --------------------------------------------------
__device__ __forceinline__ unsigned int bf16rn(float x) {
    unsigned int u = __float_as_uint(x);
    return (u + 0x7FFFu + ((u >> 16) & 1u)) >> 16;
}
__device__ __forceinline__ float bf16f(unsigned int b) {
    return __uint_as_float(b << 16);
}
__device__ __forceinline__ void split2(float x, unsigned int& h, unsigned int& l) {
    h = bf16rn(x);
    l = bf16rn(x - bf16f(h));
}

// async global(bf16) -> LDS, 16B/lane, wave-uniform LDS base
#define GLOAD16(g, l)                                                        \
    __builtin_amdgcn_global_load_lds(                                        \
        (const __attribute__((address_space(1))) unsigned int*)(g),          \
        (__attribute__((address_space(3))) unsigned int*)(l), 16, 0, 0)

// Tiled ("fragment-linear") operand layout (verified r6: 0 conflicts, full
// coalescing): matrix [ROWS][K] -> 16x32 tiles of 512 shorts (1 KB);
// tile idx = (row>>4)*(K/32)+(k>>5); elem(r, 8q+j) at q*128 + r*8 + j.
__device__ __forceinline__ size_t tiled_off(int row, int k, int ntK) {
    return ((size_t)(row >> 4) * ntK + (k >> 5)) * 512
         + ((k >> 3) & 3) * 128 + (row & 15) * 8;
}

// ===========================================================================
// PRIMARY PATH (needs 128 MiB workspace)
// ===========================================================================

// ---------------------------------------------------------------------------
// prep_fused: blockIdx.y < 32  -> enc tile: encH/encL tiled (rows=t,K=d)
//                                  + encT tiled (rows=d,K=t), hi only.
//             blockIdx.y >= 32 -> dec tile: decH/decL tiled (rows=u,K=d).
// Grid (DIM/64, 32+8, BATCH), 256 threads.
// ---------------------------------------------------------------------------
__global__ __launch_bounds__(256) void prep_fused(
    const float* __restrict__ enc, const float* __restrict__ dec,
    ushort_t* __restrict__ encH, ushort_t* __restrict__ encL,
    ushort_t* __restrict__ encT, ushort_t* __restrict__ decH,
    ushort_t* __restrict__ decL)
{
    __shared__ ushort_t T[64][72];   // [d][t] (enc branch only)

    const int b   = blockIdx.z;
    const int d0  = blockIdx.x * 64;
    const int tid = threadIdx.x;

    if (blockIdx.y < 32) {
        const int t0 = blockIdx.y * 64;
        const float* E = enc + (size_t)b * TENC * DIM;
        const size_t bofs1 = (size_t)b * TENC * DIM;
        const size_t bofs2 = (size_t)b * DIM * TENC;

        const int ltr = tid >> 2;          // 0..63 t-row
#pragma unroll
        for (int it = 0; it < 2; ++it) {
            const int c  = (tid & 3) + it * 4;   // chunk of 8 d
            const int gt = t0 + ltr;
            const int gd = d0 + c * 8;
            float4 x0 = *(const float4*)&E[(size_t)gt * DIM + gd];
            float4 x1 = *(const float4*)&E[(size_t)gt * DIM + gd + 4];
            float xs[8] = {x0.x, x0.y, x0.z, x0.w, x1.x, x1.y, x1.z, x1.w};
            unsigned int h[8], l[8];
            short8 hv, lv;
#pragma unroll
            for (int j = 0; j < 8; ++j) {
                split2(xs[j], h[j], l[j]);
                hv[j] = (short)h[j];
                lv[j] = (short)l[j];
            }
            const size_t off = bofs1 + tiled_off(gt, gd, DIM / 32);
            *(short8*)&encH[off] = hv;
            *(short8*)&encL[off] = lv;
#pragma unroll
            for (int j = 0; j < 8; ++j) T[c * 8 + j][ltr] = (ushort_t)h[j];
        }
        __syncthreads();

        const int dr = tid >> 2;           // 0..63 d-row
#pragma unroll
        for (int it = 0; it < 2; ++it) {
            const int tc = (tid & 3) + it * 4;   // chunk of 8 t
            const int gd = d0 + dr;
            const int gt = t0 + tc * 8;
            short8 v = *(const short8*)&T[dr][tc * 8];
            *(short8*)&encT[bofs2 + tiled_off(gd, gt, TENC / 32)] = v;
        }
    } else {
        const int u0 = (blockIdx.y - 32) * 64;
        const float* D = dec + (size_t)b * TDEC * DIM;
        const size_t bofs = (size_t)b * TDEC * DIM;

        const int lur = tid >> 2;          // 0..63 u-row
#pragma unroll
        for (int it = 0; it < 2; ++it) {
            const int c  = (tid & 3) + it * 4;
            const int gu = u0 + lur;
            const int gd = d0 + c * 8;
            float4 x0 = *(const float4*)&D[(size_t)gu * DIM + gd];
            float4 x1 = *(const float4*)&D[(size_t)gu * DIM + gd + 4];
            float xs[8] = {x0.x, x0.y, x0.z, x0.w, x1.x, x1.y, x1.z, x1.w};
            short8 hv, lv;
#pragma unroll
            for (int j = 0; j < 8; ++j) {
                unsigned int h, l;
                split2(xs[j], h, l);
                hv[j] = (short)h;
                lv[j] = (short)l;
            }
            const size_t off = bofs + tiled_off(gu, gd, DIM / 32);
            *(short8*)&decH[off] = hv;
            *(short8*)&decL[off] = lv;
        }
    }
}

// ---------------------------------------------------------------------------
// gemm1_lds: raw[b,t,u] = enc·dec (split-bf16) - mask. Tiled operands, fused
// per-column (max,sum-exp) partial stats -> pm/ps (located in d_out's context
// region, which is dead until reduce_ctx).
// ---------------------------------------------------------------------------
__global__ __launch_bounds__(256) void gemm1_lds(
    const ushort_t* __restrict__ encH, const ushort_t* __restrict__ encL,
    const ushort_t* __restrict__ decH, const ushort_t* __restrict__ decL,
    const int* __restrict__ mask, float* __restrict__ raw,
    float* __restrict__ pm, float* __restrict__ ps)
{
    __shared__ __align__(16) ushort_t Ah[128 * 32];
    __shared__ __align__(16) ushort_t Al[128 * 32];
    __shared__ __align__(16) ushort_t Bh[128 * 32];
    __shared__ __align__(16) ushort_t Bl[128 * 32];
    __shared__ float smx[4][68];
    __shared__ float ssx[4][68];

    const int b  = blockIdx.z;
    const int m0 = blockIdx.y * 128;   // t
    const int n0 = blockIdx.x * 128;   // u
    const int tid = threadIdx.x;

    const int lane = tid & 63;
    const int w    = tid >> 6;
    const int wm   = (w & 1) * 64;
    const int wn   = (w >> 1) * 64;
    const int lr   = lane & 15;
    const int q    = lane >> 4;
    const int l8   = lane * 8;

    const int fa = wm * 32 + q * 128 + lr * 8;
    const int fb = wn * 32 + q * 128 + lr * 8;

    const ushort_t* AH = encH + (size_t)b * TENC * DIM;
    const ushort_t* AL = encL + (size_t)b * TENC * DIM;
    const ushort_t* BH = decH + (size_t)b * TDEC * DIM;
    const ushort_t* BL = decL + (size_t)b * TDEC * DIM;
    float* C = raw + (size_t)b * TENC * TDEC;

    f32x4 acc[4][4] = {};

    for (int k0 = 0; k0 < DIM; k0 += 32) {
        __syncthreads();
#pragma unroll
        for (int q2 = 0; q2 < 2; ++q2) {
            const int rg = w * 2 + q2;
            const size_t tA = ((size_t)((m0 >> 4) + rg) * (DIM / 32) + (k0 >> 5)) * 512 + l8;
            const size_t tB = ((size_t)((n0 >> 4) + rg) * (DIM / 32) + (k0 >> 5)) * 512 + l8;
            GLOAD16(AH + tA, &Ah[rg * 512]);
            GLOAD16(AL + tA, &Al[rg * 512]);
            GLOAD16(BH + tB, &Bh[rg * 512]);
            GLOAD16(BL + tB, &Bl[rg * 512]);
        }
        __syncthreads();

        short8 ah[4], al[4], bh[4], bl[4];
#pragma unroll
        for (int i = 0; i < 4; ++i) {
            ah[i] = *(const short8*)&Ah[fa + i * 512];
            al[i] = *(const short8*)&Al[fa + i * 512];
            bh[i] = *(const short8*)&Bh[fb + i * 512];
            bl[i] = *(const short8*)&Bl[fb + i * 512];
        }
#pragma unroll
        for (int i = 0; i < 4; ++i)
#pragma unroll
            for (int j = 0; j < 4; ++j) {
                acc[i][j] = __builtin_amdgcn_mfma_f32_16x16x32_bf16(ah[i], bh[j], acc[i][j], 0, 0, 0);
                acc[i][j] = __builtin_amdgcn_mfma_f32_16x16x32_bf16(ah[i], bl[j], acc[i][j], 0, 0, 0);
                acc[i][j] = __builtin_amdgcn_mfma_f32_16x16x32_bf16(al[i], bh[j], acc[i][j], 0, 0, 0);
            }
    }

    float mkv[4][4];
#pragma unroll
    for (int i = 0; i < 4; ++i)
#pragma unroll
        for (int rr = 0; rr < 4; ++rr) {
            const int t = m0 + wm + i * 16 + q * 4 + rr;
            mkv[i][rr] = (mask[b * TENC + t] == 0) ? NEG_BIG : 0.0f;
        }

    float cm[4] = {-INFINITY, -INFINITY, -INFINITY, -INFINITY};
    float cs[4] = {0.f, 0.f, 0.f, 0.f};
#pragma unroll
    for (int i = 0; i < 4; ++i)
#pragma unroll
        for (int rr = 0; rr < 4; ++rr) {
            const int t = m0 + wm + i * 16 + q * 4 + rr;
#pragma unroll
            for (int j = 0; j < 4; ++j) {
                const int u = n0 + wn + j * 16 + lr;
                const float v = acc[i][j][rr] - mkv[i][rr];
                C[(size_t)t * TDEC + u] = v;
                cm[j] = fmaxf(cm[j], v);
            }
        }
#pragma unroll
    for (int i = 0; i < 4; ++i)
#pragma unroll
        for (int rr = 0; rr < 4; ++rr)
#pragma unroll
            for (int j = 0; j < 4; ++j)
                cs[j] += __expf(acc[i][j][rr] - mkv[i][rr] - cm[j]);

#pragma unroll
    for (int j = 0; j < 4; ++j) {
#pragma unroll
        for (int d = 16; d < 64; d <<= 1) {
            float om = __shfl_xor(cm[j], d, 64);
            float os = __shfl_xor(cs[j], d, 64);
            float mn = fmaxf(cm[j], om);
            cs[j] = cs[j] * __expf(cm[j] - mn) + os * __expf(om - mn);
            cm[j] = mn;
        }
    }

    if (q == 0) {
#pragma unroll
        for (int j = 0; j < 4; ++j) {
            smx[w][j * 16 + lr] = cm[j];
            ssx[w][j * 16 + lr] = cs[j];
        }
    }
    __syncthreads();
    if (tid < 128) {
        const int col = tid;
        const int wp  = (col >> 6) * 2;
        const int ci  = col & 63;
        const float m1 = smx[wp][ci],     s1 = ssx[wp][ci];
        const float m2 = smx[wp + 1][ci], s2 = ssx[wp + 1][ci];
        const float M = fmaxf(m1, m2);
        const float S = s1 * __expf(m1 - M) + s2 * __expf(m2 - M);
        const int idx = b * TDEC + n0 + col;
        const int tb  = m0 >> 7;
        pm[(size_t)tb * (BATCH * TDEC) + idx] = M;
        ps[(size_t)tb * (BATCH * TDEC) + idx] = S;
    }
}

// ---------------------------------------------------------------------------
// norm: fused column-stat combine (was colstat2) + scores = exp(raw-M)*inv
// in place (fp32) + scoresT tiled bf16 (rows=u, K=t).
// pm/ps live in d_out's context region -> no overlay conflict with scoresT.
// ---------------------------------------------------------------------------
__global__ __launch_bounds__(256) void norm_kernel(
    float* __restrict__ S, const float* __restrict__ pm,
    const float* __restrict__ ps, ushort_t* __restrict__ scoresT)
{
    __shared__ ushort_t T[64][72];   // [u][t]
    __shared__ float cMs[64], cIs[64];

    const int b  = blockIdx.z;
    const int t0 = blockIdx.x * 64;
    const int u0 = blockIdx.y * 64;
    const int tid = threadIdx.x;

    if (tid < 64) {
        const int idx = b * TDEC + u0 + tid;
        float M = -INFINITY;
#pragma unroll
        for (int z = 0; z < 16; ++z)
            M = fmaxf(M, pm[(size_t)z * (BATCH * TDEC) + idx]);
        float s = 0.0f;
#pragma unroll
        for (int z = 0; z < 16; ++z)
            s += ps[(size_t)z * (BATCH * TDEC) + idx] *
                 __expf(pm[(size_t)z * (BATCH * TDEC) + idx] - M);
        cMs[tid] = M;
        cIs[tid] = 1.0f / s;
    }
    __syncthreads();

    const int tr  = tid >> 4;
    const int ucl = (tid & 15) * 4;

    float4 M4 = *(const float4*)&cMs[ucl];
    float4 I4 = *(const float4*)&cIs[ucl];

    float* base = S + (size_t)b * TENC * TDEC;

#pragma unroll
    for (int i = 0; i < 4; ++i) {
        const int t = t0 + tr + 16 * i;
        float4 x = *(const float4*)&base[(size_t)t * TDEC + u0 + ucl];
        float4 p;
        p.x = __expf(x.x - M4.x) * I4.x;
        p.y = __expf(x.y - M4.y) * I4.y;
        p.z = __expf(x.z - M4.z) * I4.z;
        p.w = __expf(x.w - M4.w) * I4.w;
        *(float4*)&base[(size_t)t * TDEC + u0 + ucl] = p;
        const int tloc = tr + 16 * i;
        T[ucl + 0][tloc] = (ushort_t)bf16rn(p.x);
        T[ucl + 1][tloc] = (ushort_t)bf16rn(p.y);
        T[ucl + 2][tloc] = (ushort_t)bf16rn(p.z);
        T[ucl + 3][tloc] = (ushort_t)bf16rn(p.w);
    }
    __syncthreads();

    const size_t bofs = (size_t)b * TDEC * TENC;
    const int ur = tid >> 2;
#pragma unroll
    for (int it = 0; it < 2; ++it) {
        const int tc = (tid & 3) + it * 4;
        const int gu = u0 + ur;
        const int gt = t0 + tc * 8;
        short8 v = *(const short8*)&T[ur][tc * 8];
        *(short8*)&scoresT[bofs + tiled_off(gu, gt, TENC / 32)] = v;
    }
}

// ---------------------------------------------------------------------------
// gemm2_lds: partial[ks] = scoresT·encT^T k-slice (bf16 single), tiled
// operands, split-K=4 (no atomics). Grid (8, 4, 32): z = b*4+ks -> 1024
// blocks = 4 blocks/CU for latency hiding.
// ---------------------------------------------------------------------------
__global__ __launch_bounds__(256) void gemm2_lds(
    const ushort_t* __restrict__ scoresT, const ushort_t* __restrict__ encT,
    float* __restrict__ p0, float* __restrict__ p1,
    float* __restrict__ p2, float* __restrict__ p3)
{
    __shared__ __align__(16) ushort_t Ah[128 * 32];
    __shared__ __align__(16) ushort_t Bh[128 * 32];

    const int b  = blockIdx.z >> 2;
    const int ks = blockIdx.z & 3;
    const int m0 = blockIdx.y * 128;   // u
    const int n0 = blockIdx.x * 128;   // d
    const int tid = threadIdx.x;

    const int lane = tid & 63;
    const int w    = tid >> 6;
    const int wm   = (w & 1) * 64;
    const int wn   = (w >> 1) * 64;
    const int lr   = lane & 15;
    const int q    = lane >> 4;
    const int l8   = lane * 8;

    const int fa = wm * 32 + q * 128 + lr * 8;
    const int fb = wn * 32 + q * 128 + lr * 8;

    const ushort_t* A = scoresT + (size_t)b * TDEC * TENC;
    const ushort_t* B = encT    + (size_t)b * DIM * TENC;
    float* Psel = ks == 0 ? p0 : (ks == 1 ? p1 : (ks == 2 ? p2 : p3));
    float* P = Psel + (size_t)b * TDEC * DIM;

    const int kbeg = ks * (TENC / 4);
    const int kend = kbeg + TENC / 4;

    f32x4 acc[4][4] = {};

    for (int k0 = kbeg; k0 < kend; k0 += 32) {
        __syncthreads();
#pragma unroll
        for (int q2 = 0; q2 < 2; ++q2) {
            const int rg = w * 2 + q2;
            const size_t tA = ((size_t)((m0 >> 4) + rg) * (TENC / 32) + (k0 >> 5)) * 512 + l8;
            const size_t tB = ((size_t)((n0 >> 4) + rg) * (TENC / 32) + (k0 >> 5)) * 512 + l8;
            GLOAD16(A + tA, &Ah[rg * 512]);
            GLOAD16(B + tB, &Bh[rg * 512]);
        }
        __syncthreads();

        short8 ah[4], bh[4];
#pragma unroll
        for (int i = 0; i < 4; ++i) {
            ah[i] = *(const short8*)&Ah[fa + i * 512];
            bh[i] = *(const short8*)&Bh[fb + i * 512];
        }
#pragma unroll
        for (int i = 0; i < 4; ++i)
#pragma unroll
            for (int j = 0; j < 4; ++j)
                acc[i][j] = __builtin_amdgcn_mfma_f32_16x16x32_bf16(ah[i], bh[j], acc[i][j], 0, 0, 0);
    }

#pragma unroll
    for (int i = 0; i < 4; ++i)
#pragma unroll
        for (int rr = 0; rr < 4; ++rr) {
            const int u = m0 + wm + i * 16 + q * 4 + rr;
#pragma unroll
            for (int j = 0; j < 4; ++j) {
                const int d = n0 + wn + j * 16 + lr;
                P[(size_t)u * DIM + d] = acc[i][j][rr];
            }
        }
}

// ---------------------------------------------------------------------------
// reduce_ctx: context = p0+p1+p2+p3 (float4 streaming). 4M floats.
// ---------------------------------------------------------------------------
__global__ __launch_bounds__(256) void reduce_ctx(
    const float* __restrict__ p0, const float* __restrict__ p1,
    const float* __restrict__ p2, const float* __restrict__ p3,
    float* __restrict__ ctx)
{
    const size_t i4 = ((size_t)blockIdx.x * 256 + threadIdx.x) * 4;
    float4 a = *(const float4*)(p0 + i4);
    float4 b = *(const float4*)(p1 + i4);
    float4 c = *(const float4*)(p2 + i4);
    float4 d = *(const float4*)(p3 + i4);
    float4 o;
    o.x = a.x + b.x + c.x + d.x;
    o.y = a.y + b.y + c.y + d.y;
    o.z = a.z + b.z + c.z + d.z;
    o.w = a.w + b.w + c.w + d.w;
    *(float4*)(ctx + i4) = o;
}

// ===========================================================================
// FALLBACK PATH (round-2 proven kernels; used if workspace is too small)
// ===========================================================================

__device__ __forceinline__ void store8(ushort_t* ph, ushort_t* pl,
                                       float4 x0, float4 x1) {
    float xs[8] = {x0.x, x0.y, x0.z, x0.w, x1.x, x1.y, x1.z, x1.w};
    short8 hv, lv;
#pragma unroll
    for (int i = 0; i < 8; ++i) {
        unsigned int h, l;
        split2(xs[i], h, l);
        hv[i] = (short)h;
        lv[i] = (short)l;
    }
    *(short8*)ph = hv;
    *(short8*)pl = lv;
}

__device__ __forceinline__ void wr4(ushort_t* ph, ushort_t* pl, const float* x) {
    unsigned int h[4], l[4];
#pragma unroll
    for (int i = 0; i < 4; ++i) split2(x[i], h[i], l[i]);
    *(uint2*)ph = make_uint2(h[0] | (h[1] << 16), h[2] | (h[3] << 16));
    *(uint2*)pl = make_uint2(l[0] | (l[1] << 16), l[2] | (l[3] << 16));
}

__device__ __forceinline__ short8 frag8B(const ushort_t* p) {
    union { short8 v; uint2 u[2]; } f;
    f.u[0] = *(const uint2*)p;
    f.u[1] = *(const uint2*)(p + 4);
    return f.v;
}

__global__ __launch_bounds__(256) void gemm1_mfma(
    const float* __restrict__ enc, const float* __restrict__ dec,
    const int* __restrict__ mask, float* __restrict__ raw)
{
    __shared__ __align__(16) ushort_t Ah[128 * 32];
    __shared__ __align__(16) ushort_t Al[128 * 32];
    __shared__ __align__(16) ushort_t Bh[128 * 32];
    __shared__ __align__(16) ushort_t Bl[128 * 32];

    const int b  = blockIdx.z;
    const int m0 = blockIdx.y * 128;
    const int n0 = blockIdx.x * 128;
    const int tid = threadIdx.x;

    const float* A  = enc + (size_t)b * TENC * DIM;
    const float* Bg = dec + (size_t)b * TDEC * DIM;
    float*       C  = raw + (size_t)b * TENC * TDEC;

    const int lane = tid & 63;
    const int wv   = tid >> 6;
    const int wm   = (wv & 1) * 64;
    const int wn   = (wv >> 1) * 64;
    const int lr   = lane & 15;
    const int q    = lane >> 4;

    const int r0 = tid >> 2;
    const int c8 = (tid & 3) * 8;

    f32x4 acc[4][4] = {};

    for (int k0 = 0; k0 < DIM; k0 += 32) {
        const float* pa0 = A  + (size_t)(m0 + r0) * DIM + k0 + c8;
        const float* pa1 = A  + (size_t)(m0 + r0 + 64) * DIM + k0 + c8;
        const float* pb0 = Bg + (size_t)(n0 + r0) * DIM + k0 + c8;
        const float* pb1 = Bg + (size_t)(n0 + r0 + 64) * DIM + k0 + c8;
        float4 a0 = *(const float4*)pa0, a0b = *(const float4*)(pa0 + 4);
        float4 a1 = *(const float4*)pa1, a1b = *(const float4*)(pa1 + 4);
        float4 b0 = *(const float4*)pb0, b0b = *(const float4*)(pb0 + 4);
        float4 b1 = *(const float4*)pb1, b1b = *(const float4*)(pb1 + 4);

        __syncthreads();
        store8(&Ah[r0 * 32 + c8],        &Al[r0 * 32 + c8],        a0, a0b);
        store8(&Ah[(r0 + 64) * 32 + c8], &Al[(r0 + 64) * 32 + c8], a1, a1b);
        store8(&Bh[r0 * 32 + c8],        &Bl[r0 * 32 + c8],        b0, b0b);
        store8(&Bh[(r0 + 64) * 32 + c8], &Bl[(r0 + 64) * 32 + c8], b1, b1b);
        __syncthreads();

        short8 ah[4], al[4], bh[4], bl[4];
#pragma unroll
        for (int i = 0; i < 4; ++i) {
            ah[i] = *(const short8*)&Ah[(wm + i * 16 + lr) * 32 + q * 8];
            al[i] = *(const short8*)&Al[(wm + i * 16 + lr) * 32 + q * 8];
            bh[i] = *(const short8*)&Bh[(wn + i * 16 + lr) * 32 + q * 8];
            bl[i] = *(const short8*)&Bl[(wn + i * 16 + lr) * 32 + q * 8];
        }
#pragma unroll
        for (int i = 0; i < 4; ++i)
#pragma unroll
            for (int j = 0; j < 4; ++j) {
                acc[i][j] = __builtin_amdgcn_mfma_f32_16x16x32_bf16(ah[i], bh[j], acc[i][j], 0, 0, 0);
                acc[i][j] = __builtin_amdgcn_mfma_f32_16x16x32_bf16(ah[i], bl[j], acc[i][j], 0, 0, 0);
                acc[i][j] = __builtin_amdgcn_mfma_f32_16x16x32_bf16(al[i], bh[j], acc[i][j], 0, 0, 0);
            }
    }

#pragma unroll
    for (int i = 0; i < 4; ++i)
#pragma unroll
        for (int rr = 0; rr < 4; ++rr) {
            const int t = m0 + wm + i * 16 + q * 4 + rr;
            const float mk = (mask[b * TENC + t] == 0) ? NEG_BIG : 0.0f;
#pragma unroll
            for (int j = 0; j < 4; ++j) {
                const int u = n0 + wn + j * 16 + lr;
                C[(size_t)t * TDEC + u] = acc[i][j][rr] - mk;
            }
        }
}

__global__ __launch_bounds__(256) void softmax_kernel(float* __restrict__ S)
{
    const int b  = blockIdx.y;
    const int u0 = blockIdx.x * 16;
    const int up = threadIdx.x & 15;
    const int tg = threadIdx.x >> 4;

    float* col = S + (size_t)b * TENC * TDEC + u0;

    float m = -INFINITY, s = 0.0f;
    for (int t = tg; t < TENC; t += 16) {
        float x = col[(size_t)t * TDEC + up];
        float mn = fmaxf(m, x);
        s = s * __expf(m - mn) + __expf(x - mn);
        m = mn;
    }

    __shared__ float sm[16][17];
    __shared__ float ss[16][17];
    sm[tg][up] = m;
    ss[tg][up] = s;
    __syncthreads();

    float M = -INFINITY;
#pragma unroll
    for (int j = 0; j < 16; ++j) M = fmaxf(M, sm[j][up]);
    float sum = 0.0f;
#pragma unroll
    for (int j = 0; j < 16; ++j) sum += ss[j][up] * __expf(sm[j][up] - M);
    const float inv = 1.0f / sum;

    for (int t = tg; t < TENC; t += 16) {
        float x = col[(size_t)t * TDEC + up];
        col[(size_t)t * TDEC + up] = __expf(x - M) * inv;
    }
}

#define G2_LD 36

__global__ __launch_bounds__(256) void gemm2_mfma(
    const float* __restrict__ scores, const float* __restrict__ enc,
    float* __restrict__ context)
{
    __shared__ __align__(16) ushort_t Ah[128 * G2_LD];
    __shared__ __align__(16) ushort_t Al[128 * G2_LD];
    __shared__ __align__(16) ushort_t Bh[128 * G2_LD];
    __shared__ __align__(16) ushort_t Bl[128 * G2_LD];

    const int b  = blockIdx.z;
    const int m0 = blockIdx.y * 128;
    const int n0 = blockIdx.x * 128;
    const int tid = threadIdx.x;

    const float* S = scores + (size_t)b * TENC * TDEC;
    const float* E = enc    + (size_t)b * TENC * DIM;
    float*       C = context + (size_t)b * TDEC * DIM;

    const int lane = tid & 63;
    const int wv   = tid >> 6;
    const int wm   = (wv & 1) * 64;
    const int wn   = (wv >> 1) * 64;
    const int lr   = lane & 15;
    const int q    = lane >> 4;

    const int ul = tid & 127;
    const int th = (tid >> 7) * 16;

    f32x4 acc[4][4] = {};

    for (int k0 = 0; k0 < TENC; k0 += 32) {
        float av[16], bv[16];
#pragma unroll
        for (int i = 0; i < 4; ++i) {
            const int t = k0 + th + i * 4;
#pragma unroll
            for (int j = 0; j < 4; ++j) {
                av[i * 4 + j] = S[(size_t)(t + j) * TDEC + m0 + ul];
                bv[i * 4 + j] = E[(size_t)(t + j) * DIM + n0 + ul];
            }
        }
        __syncthreads();
#pragma unroll
        for (int i = 0; i < 4; ++i) {
            const int tt = th + i * 4;
            wr4(&Ah[ul * G2_LD + tt], &Al[ul * G2_LD + tt], &av[i * 4]);
            wr4(&Bh[ul * G2_LD + tt], &Bl[ul * G2_LD + tt], &bv[i * 4]);
        }
        __syncthreads();

        short8 ah[4], al[4], bh[4], bl[4];
#pragma unroll
        for (int i = 0; i < 4; ++i) {
            ah[i] = frag8B(&Ah[(wm + i * 16 + lr) * G2_LD + q * 8]);
            al[i] = frag8B(&Al[(wm + i * 16 + lr) * G2_LD + q * 8]);
            bh[i] = frag8B(&Bh[(wn + i * 16 + lr) * G2_LD + q * 8]);
            bl[i] = frag8B(&Bl[(wn + i * 16 + lr) * G2_LD + q * 8]);
        }
#pragma unroll
        for (int i = 0; i < 4; ++i)
#pragma unroll
            for (int j = 0; j < 4; ++j) {
                acc[i][j] = __builtin_amdgcn_mfma_f32_16x16x32_bf16(ah[i], bh[j], acc[i][j], 0, 0, 0);
                acc[i][j] = __builtin_amdgcn_mfma_f32_16x16x32_bf16(ah[i], bl[j], acc[i][j], 0, 0, 0);
                acc[i][j] = __builtin_amdgcn_mfma_f32_16x16x32_bf16(al[i], bh[j], acc[i][j], 0, 0, 0);
            }
    }

#pragma unroll
    for (int i = 0; i < 4; ++i)
#pragma unroll
        for (int rr = 0; rr < 4; ++rr) {
            const int u = m0 + wm + i * 16 + q * 4 + rr;
#pragma unroll
            for (int j = 0; j < 4; ++j) {
                const int d = n0 + wn + j * 16 + lr;
                C[(size_t)u * DIM + d] = acc[i][j][rr];
            }
        }
}

// ===========================================================================
extern "C" void kernel_launch(void* const* d_in, const int* in_sizes, int n_in,
                              void* d_out, int out_size, void* d_ws, size_t ws_size,
                              hipStream_t stream)
{
    const float* enc      = (const float*)d_in[0];
    const int*   enc_mask = (const int*)  d_in[1];
    const float* dec      = (const float*)d_in[2];

    float* context = (float*)d_out;                        // B*TDEC*DIM
    float* scores  = context + (size_t)BATCH * TDEC * DIM; // B*TENC*TDEC

    // Workspace layout (bytes). p0..p3 overlay encH/encL (dead after gemm1).
    // pm/ps live in d_out's context region (dead until reduce_ctx overwrites).
    const size_t OFF_ENC_H = 0;          // 32 MiB
    const size_t OFF_ENC_L = 33554432;   // 32 MiB
    const size_t OFF_DEC_H = 67108864;   // 8 MiB
    const size_t OFF_DEC_L = 75497472;   // 8 MiB
    const size_t OFF_ENC_T = 83886080;   // 32 MiB
    const size_t OFF_SCO_T = 117440512;  // 16 MiB
    const size_t WS_NEED   = 134217728;  // 128 MiB

    if (ws_size >= WS_NEED) {
        char* w = (char*)d_ws;
        ushort_t* encH    = (ushort_t*)(w + OFF_ENC_H);
        ushort_t* encL    = (ushort_t*)(w + OFF_ENC_L);
        ushort_t* decH    = (ushort_t*)(w + OFF_DEC_H);
        ushort_t* decL    = (ushort_t*)(w + OFF_DEC_L);
        ushort_t* encT    = (ushort_t*)(w + OFF_ENC_T);
        ushort_t* scoresT = (ushort_t*)(w + OFF_SCO_T);
        float*    part0   = (float*)(w + OFF_ENC_H);          // 16 MiB each
        float*    part1   = (float*)(w + OFF_ENC_H + 16777216);
        float*    part2   = (float*)(w + OFF_ENC_L);
        float*    part3   = (float*)(w + OFF_ENC_L + 16777216);
        float*    pm      = context;                // 256 KB, in d_out
        float*    ps      = context + 65536;        // 256 KB, in d_out

        prep_fused<<<dim3(DIM / 64, 40, BATCH), 256, 0, stream>>>(
            enc, dec, encH, encL, encT, decH, decL);

        gemm1_lds<<<dim3(TDEC / 128, TENC / 128, BATCH), 256, 0, stream>>>(
            encH, encL, decH, decL, enc_mask, scores, pm, ps);

        norm_kernel<<<dim3(TENC / 64, TDEC / 64, BATCH), 256, 0, stream>>>(
            scores, pm, ps, scoresT);

        gemm2_lds<<<dim3(DIM / 128, TDEC / 128, BATCH * 4), 256, 0, stream>>>(
            scoresT, encT, part0, part1, part2, part3);

        reduce_ctx<<<4096, 256, 0, stream>>>(part0, part1, part2, part3, context);
    } else {
        gemm1_mfma<<<dim3(TDEC / 128, TENC / 128, BATCH), 256, 0, stream>>>(
            enc, dec, enc_mask, scores);
        softmax_kernel<<<dim3(TDEC / 16, BATCH), 256, 0, stream>>>(scores);
        gemm2_mfma<<<dim3(DIM / 128, TDEC / 128, BATCH), 256, 0, stream>>>(
            scores, enc, context);
    }
}

// Round 8
// 233.207 us; speedup vs baseline: 1.0432x; 1.0432x over previous
//
#include <hip/hip_runtime.h>
#include <math.h>

#define BATCH 8
#define TENC 2048
#define TDEC 512
#define DIM 1024
#define NEG_BIG 1e20f

typedef __attribute__((ext_vector_type(8))) short short8;
typedef __attribute__((ext_vector_type(4))) float f32x4;
typedef unsigned short ushort_t;

// ---- fp32 -> bf16 helpers --------------------------------------------------
__device__ __forceinline__ unsigned int bf16rn(float x) {
    unsigned int u = __float_as_uint(x);
    return (u + 0x7FFFu + ((u >> 16) & 1u)) >> 16;
}
__device__ __forceinline__ float bf16f(unsigned int b) {
    return __uint_as_float(b << 16);
}
__device__ __forceinline__ void split2(float x, unsigned int& h, unsigned int& l) {
    h = bf16rn(x);
    l = bf16rn(x - bf16f(h));
}

// async global(bf16) -> LDS, 16B/lane, wave-uniform LDS base
#define GLOAD16(g, l)                                                        \
    __builtin_amdgcn_global_load_lds(                                        \
        (const __attribute__((address_space(1))) unsigned int*)(g),          \
        (__attribute__((address_space(3))) unsigned int*)(l), 16, 0, 0)

// Tiled ("fragment-linear") operand layout (verified r6: 0 conflicts, full
// coalescing): matrix [ROWS][K] -> 16x32 tiles of 512 shorts (1 KB);
// tile idx = (row>>4)*(K/32)+(k>>5); elem(r, 8q+j) at q*128 + r*8 + j.
__device__ __forceinline__ size_t tiled_off(int row, int k, int ntK) {
    return ((size_t)(row >> 4) * ntK + (k >> 5)) * 512
         + ((k >> 3) & 3) * 128 + (row & 15) * 8;
}

// ===========================================================================
// PRIMARY PATH (needs 128 MiB workspace)
// ===========================================================================

// ---------------------------------------------------------------------------
// prep_fused: blockIdx.y < 32  -> enc tile: encH/encL tiled (rows=t,K=d)
//                                  + encT tiled (rows=d,K=t), hi only.
//             blockIdx.y >= 32 -> dec tile: decH/decL tiled (rows=u,K=d).
// Grid (DIM/64, 32+8, BATCH), 256 threads.
// ---------------------------------------------------------------------------
__global__ __launch_bounds__(256) void prep_fused(
    const float* __restrict__ enc, const float* __restrict__ dec,
    ushort_t* __restrict__ encH, ushort_t* __restrict__ encL,
    ushort_t* __restrict__ encT, ushort_t* __restrict__ decH,
    ushort_t* __restrict__ decL)
{
    __shared__ ushort_t T[64][72];   // [d][t] (enc branch only)

    const int b   = blockIdx.z;
    const int d0  = blockIdx.x * 64;
    const int tid = threadIdx.x;

    if (blockIdx.y < 32) {
        const int t0 = blockIdx.y * 64;
        const float* E = enc + (size_t)b * TENC * DIM;
        const size_t bofs1 = (size_t)b * TENC * DIM;
        const size_t bofs2 = (size_t)b * DIM * TENC;

        const int ltr = tid >> 2;          // 0..63 t-row
#pragma unroll
        for (int it = 0; it < 2; ++it) {
            const int c  = (tid & 3) + it * 4;   // chunk of 8 d
            const int gt = t0 + ltr;
            const int gd = d0 + c * 8;
            float4 x0 = *(const float4*)&E[(size_t)gt * DIM + gd];
            float4 x1 = *(const float4*)&E[(size_t)gt * DIM + gd + 4];
            float xs[8] = {x0.x, x0.y, x0.z, x0.w, x1.x, x1.y, x1.z, x1.w};
            unsigned int h[8], l[8];
            short8 hv, lv;
#pragma unroll
            for (int j = 0; j < 8; ++j) {
                split2(xs[j], h[j], l[j]);
                hv[j] = (short)h[j];
                lv[j] = (short)l[j];
            }
            const size_t off = bofs1 + tiled_off(gt, gd, DIM / 32);
            *(short8*)&encH[off] = hv;
            *(short8*)&encL[off] = lv;
#pragma unroll
            for (int j = 0; j < 8; ++j) T[c * 8 + j][ltr] = (ushort_t)h[j];
        }
        __syncthreads();

        const int dr = tid >> 2;           // 0..63 d-row
#pragma unroll
        for (int it = 0; it < 2; ++it) {
            const int tc = (tid & 3) + it * 4;   // chunk of 8 t
            const int gd = d0 + dr;
            const int gt = t0 + tc * 8;
            short8 v = *(const short8*)&T[dr][tc * 8];
            *(short8*)&encT[bofs2 + tiled_off(gd, gt, TENC / 32)] = v;
        }
    } else {
        const int u0 = (blockIdx.y - 32) * 64;
        const float* D = dec + (size_t)b * TDEC * DIM;
        const size_t bofs = (size_t)b * TDEC * DIM;

        const int lur = tid >> 2;          // 0..63 u-row
#pragma unroll
        for (int it = 0; it < 2; ++it) {
            const int c  = (tid & 3) + it * 4;
            const int gu = u0 + lur;
            const int gd = d0 + c * 8;
            float4 x0 = *(const float4*)&D[(size_t)gu * DIM + gd];
            float4 x1 = *(const float4*)&D[(size_t)gu * DIM + gd + 4];
            float xs[8] = {x0.x, x0.y, x0.z, x0.w, x1.x, x1.y, x1.z, x1.w};
            short8 hv, lv;
#pragma unroll
            for (int j = 0; j < 8; ++j) {
                unsigned int h, l;
                split2(xs[j], h, l);
                hv[j] = (short)h;
                lv[j] = (short)l;
            }
            const size_t off = bofs + tiled_off(gu, gd, DIM / 32);
            *(short8*)&decH[off] = hv;
            *(short8*)&decL[off] = lv;
        }
    }
}

// ---------------------------------------------------------------------------
// gemm1_lds: raw[b,t,u] = enc·dec (split-bf16) - mask. Tiled operands.
// XCD-batch affinity: grid (BATCH, TENC/128, TDEC/128) -> linear block id
// % 8 == batch, so each XCD serves one batch (dec slice 2 MB fits its L2;
// enc tiles shared by the 4 co-resident u-tiles hit L2 too).
// Fused per-column (max,sum-exp) partial stats -> pm/ps (in d_out's context
// region, dead until reduce_ctx).
// ---------------------------------------------------------------------------
__global__ __launch_bounds__(256) void gemm1_lds(
    const ushort_t* __restrict__ encH, const ushort_t* __restrict__ encL,
    const ushort_t* __restrict__ decH, const ushort_t* __restrict__ decL,
    const int* __restrict__ mask, float* __restrict__ raw,
    float* __restrict__ pm, float* __restrict__ ps)
{
    __shared__ __align__(16) ushort_t Ah[128 * 32];
    __shared__ __align__(16) ushort_t Al[128 * 32];
    __shared__ __align__(16) ushort_t Bh[128 * 32];
    __shared__ __align__(16) ushort_t Bl[128 * 32];
    __shared__ float smx[4][68];
    __shared__ float ssx[4][68];

    const int b  = blockIdx.x;         // batch -> XCD affinity
    const int m0 = blockIdx.y * 128;   // t
    const int n0 = blockIdx.z * 128;   // u
    const int tid = threadIdx.x;

    const int lane = tid & 63;
    const int w    = tid >> 6;
    const int wm   = (w & 1) * 64;
    const int wn   = (w >> 1) * 64;
    const int lr   = lane & 15;
    const int q    = lane >> 4;
    const int l8   = lane * 8;

    const int fa = wm * 32 + q * 128 + lr * 8;
    const int fb = wn * 32 + q * 128 + lr * 8;

    const ushort_t* AH = encH + (size_t)b * TENC * DIM;
    const ushort_t* AL = encL + (size_t)b * TENC * DIM;
    const ushort_t* BH = decH + (size_t)b * TDEC * DIM;
    const ushort_t* BL = decL + (size_t)b * TDEC * DIM;
    float* C = raw + (size_t)b * TENC * TDEC;

    f32x4 acc[4][4] = {};

    for (int k0 = 0; k0 < DIM; k0 += 32) {
        __syncthreads();
#pragma unroll
        for (int q2 = 0; q2 < 2; ++q2) {
            const int rg = w * 2 + q2;
            const size_t tA = ((size_t)((m0 >> 4) + rg) * (DIM / 32) + (k0 >> 5)) * 512 + l8;
            const size_t tB = ((size_t)((n0 >> 4) + rg) * (DIM / 32) + (k0 >> 5)) * 512 + l8;
            GLOAD16(AH + tA, &Ah[rg * 512]);
            GLOAD16(AL + tA, &Al[rg * 512]);
            GLOAD16(BH + tB, &Bh[rg * 512]);
            GLOAD16(BL + tB, &Bl[rg * 512]);
        }
        __syncthreads();

        short8 ah[4], al[4], bh[4], bl[4];
#pragma unroll
        for (int i = 0; i < 4; ++i) {
            ah[i] = *(const short8*)&Ah[fa + i * 512];
            al[i] = *(const short8*)&Al[fa + i * 512];
            bh[i] = *(const short8*)&Bh[fb + i * 512];
            bl[i] = *(const short8*)&Bl[fb + i * 512];
        }
#pragma unroll
        for (int i = 0; i < 4; ++i)
#pragma unroll
            for (int j = 0; j < 4; ++j) {
                acc[i][j] = __builtin_amdgcn_mfma_f32_16x16x32_bf16(ah[i], bh[j], acc[i][j], 0, 0, 0);
                acc[i][j] = __builtin_amdgcn_mfma_f32_16x16x32_bf16(ah[i], bl[j], acc[i][j], 0, 0, 0);
                acc[i][j] = __builtin_amdgcn_mfma_f32_16x16x32_bf16(al[i], bh[j], acc[i][j], 0, 0, 0);
            }
    }

    float mkv[4][4];
#pragma unroll
    for (int i = 0; i < 4; ++i)
#pragma unroll
        for (int rr = 0; rr < 4; ++rr) {
            const int t = m0 + wm + i * 16 + q * 4 + rr;
            mkv[i][rr] = (mask[b * TENC + t] == 0) ? NEG_BIG : 0.0f;
        }

    float cm[4] = {-INFINITY, -INFINITY, -INFINITY, -INFINITY};
    float cs[4] = {0.f, 0.f, 0.f, 0.f};
#pragma unroll
    for (int i = 0; i < 4; ++i)
#pragma unroll
        for (int rr = 0; rr < 4; ++rr) {
            const int t = m0 + wm + i * 16 + q * 4 + rr;
#pragma unroll
            for (int j = 0; j < 4; ++j) {
                const int u = n0 + wn + j * 16 + lr;
                const float v = acc[i][j][rr] - mkv[i][rr];
                C[(size_t)t * TDEC + u] = v;
                cm[j] = fmaxf(cm[j], v);
            }
        }
#pragma unroll
    for (int i = 0; i < 4; ++i)
#pragma unroll
        for (int rr = 0; rr < 4; ++rr)
#pragma unroll
            for (int j = 0; j < 4; ++j)
                cs[j] += __expf(acc[i][j][rr] - mkv[i][rr] - cm[j]);

#pragma unroll
    for (int j = 0; j < 4; ++j) {
#pragma unroll
        for (int d = 16; d < 64; d <<= 1) {
            float om = __shfl_xor(cm[j], d, 64);
            float os = __shfl_xor(cs[j], d, 64);
            float mn = fmaxf(cm[j], om);
            cs[j] = cs[j] * __expf(cm[j] - mn) + os * __expf(om - mn);
            cm[j] = mn;
        }
    }

    if (q == 0) {
#pragma unroll
        for (int j = 0; j < 4; ++j) {
            smx[w][j * 16 + lr] = cm[j];
            ssx[w][j * 16 + lr] = cs[j];
        }
    }
    __syncthreads();
    if (tid < 128) {
        const int col = tid;
        const int wp  = (col >> 6) * 2;
        const int ci  = col & 63;
        const float m1 = smx[wp][ci],     s1 = ssx[wp][ci];
        const float m2 = smx[wp + 1][ci], s2 = ssx[wp + 1][ci];
        const float M = fmaxf(m1, m2);
        const float S = s1 * __expf(m1 - M) + s2 * __expf(m2 - M);
        const int idx = b * TDEC + n0 + col;
        const int tb  = m0 >> 7;
        pm[(size_t)tb * (BATCH * TDEC) + idx] = M;
        ps[(size_t)tb * (BATCH * TDEC) + idx] = S;
    }
}

// ---------------------------------------------------------------------------
// norm: fused column-stat combine + scores = exp(raw-M)*inv in place (fp32)
// + scoresT tiled bf16 (rows=u, K=t).
// ---------------------------------------------------------------------------
__global__ __launch_bounds__(256) void norm_kernel(
    float* __restrict__ S, const float* __restrict__ pm,
    const float* __restrict__ ps, ushort_t* __restrict__ scoresT)
{
    __shared__ ushort_t T[64][72];   // [u][t]
    __shared__ float cMs[64], cIs[64];

    const int b  = blockIdx.z;
    const int t0 = blockIdx.x * 64;
    const int u0 = blockIdx.y * 64;
    const int tid = threadIdx.x;

    if (tid < 64) {
        const int idx = b * TDEC + u0 + tid;
        float M = -INFINITY;
#pragma unroll
        for (int z = 0; z < 16; ++z)
            M = fmaxf(M, pm[(size_t)z * (BATCH * TDEC) + idx]);
        float s = 0.0f;
#pragma unroll
        for (int z = 0; z < 16; ++z)
            s += ps[(size_t)z * (BATCH * TDEC) + idx] *
                 __expf(pm[(size_t)z * (BATCH * TDEC) + idx] - M);
        cMs[tid] = M;
        cIs[tid] = 1.0f / s;
    }
    __syncthreads();

    const int tr  = tid >> 4;
    const int ucl = (tid & 15) * 4;

    float4 M4 = *(const float4*)&cMs[ucl];
    float4 I4 = *(const float4*)&cIs[ucl];

    float* base = S + (size_t)b * TENC * TDEC;

#pragma unroll
    for (int i = 0; i < 4; ++i) {
        const int t = t0 + tr + 16 * i;
        float4 x = *(const float4*)&base[(size_t)t * TDEC + u0 + ucl];
        float4 p;
        p.x = __expf(x.x - M4.x) * I4.x;
        p.y = __expf(x.y - M4.y) * I4.y;
        p.z = __expf(x.z - M4.z) * I4.z;
        p.w = __expf(x.w - M4.w) * I4.w;
        *(float4*)&base[(size_t)t * TDEC + u0 + ucl] = p;
        const int tloc = tr + 16 * i;
        T[ucl + 0][tloc] = (ushort_t)bf16rn(p.x);
        T[ucl + 1][tloc] = (ushort_t)bf16rn(p.y);
        T[ucl + 2][tloc] = (ushort_t)bf16rn(p.z);
        T[ucl + 3][tloc] = (ushort_t)bf16rn(p.w);
    }
    __syncthreads();

    const size_t bofs = (size_t)b * TDEC * TENC;
    const int ur = tid >> 2;
#pragma unroll
    for (int it = 0; it < 2; ++it) {
        const int tc = (tid & 3) + it * 4;
        const int gu = u0 + ur;
        const int gt = t0 + tc * 8;
        short8 v = *(const short8*)&T[ur][tc * 8];
        *(short8*)&scoresT[bofs + tiled_off(gu, gt, TENC / 32)] = v;
    }
}

// ---------------------------------------------------------------------------
// gemm2_lds: bf16 partial[ks] = scoresT·encT^T k-slice, tiled operands,
// split-K=4, no atomics. XCD-batch affinity: grid (BATCH, 32, 4):
// x = b, y = ks*8 + d-tile, z = u-tile. Partials stored bf16 (halves traffic;
// adds <=0.01 absmax).
// ---------------------------------------------------------------------------
__global__ __launch_bounds__(256) void gemm2_lds(
    const ushort_t* __restrict__ scoresT, const ushort_t* __restrict__ encT,
    ushort_t* __restrict__ p0, ushort_t* __restrict__ p1,
    ushort_t* __restrict__ p2, ushort_t* __restrict__ p3)
{
    __shared__ __align__(16) ushort_t Ah[128 * 32];
    __shared__ __align__(16) ushort_t Bh[128 * 32];

    const int b  = blockIdx.x;             // batch -> XCD affinity
    const int ks = blockIdx.y >> 3;
    const int n0 = (blockIdx.y & 7) * 128; // d
    const int m0 = blockIdx.z * 128;       // u
    const int tid = threadIdx.x;

    const int lane = tid & 63;
    const int w    = tid >> 6;
    const int wm   = (w & 1) * 64;
    const int wn   = (w >> 1) * 64;
    const int lr   = lane & 15;
    const int q    = lane >> 4;
    const int l8   = lane * 8;

    const int fa = wm * 32 + q * 128 + lr * 8;
    const int fb = wn * 32 + q * 128 + lr * 8;

    const ushort_t* A = scoresT + (size_t)b * TDEC * TENC;
    const ushort_t* B = encT    + (size_t)b * DIM * TENC;
    ushort_t* Psel = ks == 0 ? p0 : (ks == 1 ? p1 : (ks == 2 ? p2 : p3));
    ushort_t* P = Psel + (size_t)b * TDEC * DIM;

    const int kbeg = ks * (TENC / 4);
    const int kend = kbeg + TENC / 4;

    f32x4 acc[4][4] = {};

    for (int k0 = kbeg; k0 < kend; k0 += 32) {
        __syncthreads();
#pragma unroll
        for (int q2 = 0; q2 < 2; ++q2) {
            const int rg = w * 2 + q2;
            const size_t tA = ((size_t)((m0 >> 4) + rg) * (TENC / 32) + (k0 >> 5)) * 512 + l8;
            const size_t tB = ((size_t)((n0 >> 4) + rg) * (TENC / 32) + (k0 >> 5)) * 512 + l8;
            GLOAD16(A + tA, &Ah[rg * 512]);
            GLOAD16(B + tB, &Bh[rg * 512]);
        }
        __syncthreads();

        short8 ah[4], bh[4];
#pragma unroll
        for (int i = 0; i < 4; ++i) {
            ah[i] = *(const short8*)&Ah[fa + i * 512];
            bh[i] = *(const short8*)&Bh[fb + i * 512];
        }
#pragma unroll
        for (int i = 0; i < 4; ++i)
#pragma unroll
            for (int j = 0; j < 4; ++j)
                acc[i][j] = __builtin_amdgcn_mfma_f32_16x16x32_bf16(ah[i], bh[j], acc[i][j], 0, 0, 0);
    }

#pragma unroll
    for (int i = 0; i < 4; ++i)
#pragma unroll
        for (int rr = 0; rr < 4; ++rr) {
            const int u = m0 + wm + i * 16 + q * 4 + rr;
#pragma unroll
            for (int j = 0; j < 4; ++j) {
                const int d = n0 + wn + j * 16 + lr;
                P[(size_t)u * DIM + d] = (ushort_t)bf16rn(acc[i][j][rr]);
            }
        }
}

// ---------------------------------------------------------------------------
// reduce_ctx: context = sum of 4 bf16 partials (fp32 accumulate). 4M floats;
// each thread handles 8 elements. Grid 2048.
// ---------------------------------------------------------------------------
__global__ __launch_bounds__(256) void reduce_ctx(
    const ushort_t* __restrict__ p0, const ushort_t* __restrict__ p1,
    const ushort_t* __restrict__ p2, const ushort_t* __restrict__ p3,
    float* __restrict__ ctx)
{
    const size_t i8 = ((size_t)blockIdx.x * 256 + threadIdx.x) * 8;
    short8 a = *(const short8*)(p0 + i8);
    short8 b = *(const short8*)(p1 + i8);
    short8 c = *(const short8*)(p2 + i8);
    short8 d = *(const short8*)(p3 + i8);
    float o[8];
#pragma unroll
    for (int j = 0; j < 8; ++j)
        o[j] = bf16f((unsigned short)a[j]) + bf16f((unsigned short)b[j])
             + bf16f((unsigned short)c[j]) + bf16f((unsigned short)d[j]);
    *(float4*)(ctx + i8)     = make_float4(o[0], o[1], o[2], o[3]);
    *(float4*)(ctx + i8 + 4) = make_float4(o[4], o[5], o[6], o[7]);
}

// ===========================================================================
// FALLBACK PATH (round-2 proven kernels; used if workspace is too small)
// ===========================================================================

__device__ __forceinline__ void store8(ushort_t* ph, ushort_t* pl,
                                       float4 x0, float4 x1) {
    float xs[8] = {x0.x, x0.y, x0.z, x0.w, x1.x, x1.y, x1.z, x1.w};
    short8 hv, lv;
#pragma unroll
    for (int i = 0; i < 8; ++i) {
        unsigned int h, l;
        split2(xs[i], h, l);
        hv[i] = (short)h;
        lv[i] = (short)l;
    }
    *(short8*)ph = hv;
    *(short8*)pl = lv;
}

__device__ __forceinline__ void wr4(ushort_t* ph, ushort_t* pl, const float* x) {
    unsigned int h[4], l[4];
#pragma unroll
    for (int i = 0; i < 4; ++i) split2(x[i], h[i], l[i]);
    *(uint2*)ph = make_uint2(h[0] | (h[1] << 16), h[2] | (h[3] << 16));
    *(uint2*)pl = make_uint2(l[0] | (l[1] << 16), l[2] | (l[3] << 16));
}

__device__ __forceinline__ short8 frag8B(const ushort_t* p) {
    union { short8 v; uint2 u[2]; } f;
    f.u[0] = *(const uint2*)p;
    f.u[1] = *(const uint2*)(p + 4);
    return f.v;
}

__global__ __launch_bounds__(256) void gemm1_mfma(
    const float* __restrict__ enc, const float* __restrict__ dec,
    const int* __restrict__ mask, float* __restrict__ raw)
{
    __shared__ __align__(16) ushort_t Ah[128 * 32];
    __shared__ __align__(16) ushort_t Al[128 * 32];
    __shared__ __align__(16) ushort_t Bh[128 * 32];
    __shared__ __align__(16) ushort_t Bl[128 * 32];

    const int b  = blockIdx.z;
    const int m0 = blockIdx.y * 128;
    const int n0 = blockIdx.x * 128;
    const int tid = threadIdx.x;

    const float* A  = enc + (size_t)b * TENC * DIM;
    const float* Bg = dec + (size_t)b * TDEC * DIM;
    float*       C  = raw + (size_t)b * TENC * TDEC;

    const int lane = tid & 63;
    const int wv   = tid >> 6;
    const int wm   = (wv & 1) * 64;
    const int wn   = (wv >> 1) * 64;
    const int lr   = lane & 15;
    const int q    = lane >> 4;

    const int r0 = tid >> 2;
    const int c8 = (tid & 3) * 8;

    f32x4 acc[4][4] = {};

    for (int k0 = 0; k0 < DIM; k0 += 32) {
        const float* pa0 = A  + (size_t)(m0 + r0) * DIM + k0 + c8;
        const float* pa1 = A  + (size_t)(m0 + r0 + 64) * DIM + k0 + c8;
        const float* pb0 = Bg + (size_t)(n0 + r0) * DIM + k0 + c8;
        const float* pb1 = Bg + (size_t)(n0 + r0 + 64) * DIM + k0 + c8;
        float4 a0 = *(const float4*)pa0, a0b = *(const float4*)(pa0 + 4);
        float4 a1 = *(const float4*)pa1, a1b = *(const float4*)(pa1 + 4);
        float4 b0 = *(const float4*)pb0, b0b = *(const float4*)(pb0 + 4);
        float4 b1 = *(const float4*)pb1, b1b = *(const float4*)(pb1 + 4);

        __syncthreads();
        store8(&Ah[r0 * 32 + c8],        &Al[r0 * 32 + c8],        a0, a0b);
        store8(&Ah[(r0 + 64) * 32 + c8], &Al[(r0 + 64) * 32 + c8], a1, a1b);
        store8(&Bh[r0 * 32 + c8],        &Bl[r0 * 32 + c8],        b0, b0b);
        store8(&Bh[(r0 + 64) * 32 + c8], &Bl[(r0 + 64) * 32 + c8], b1, b1b);
        __syncthreads();

        short8 ah[4], al[4], bh[4], bl[4];
#pragma unroll
        for (int i = 0; i < 4; ++i) {
            ah[i] = *(const short8*)&Ah[(wm + i * 16 + lr) * 32 + q * 8];
            al[i] = *(const short8*)&Al[(wm + i * 16 + lr) * 32 + q * 8];
            bh[i] = *(const short8*)&Bh[(wn + i * 16 + lr) * 32 + q * 8];
            bl[i] = *(const short8*)&Bl[(wn + i * 16 + lr) * 32 + q * 8];
        }
#pragma unroll
        for (int i = 0; i < 4; ++i)
#pragma unroll
            for (int j = 0; j < 4; ++j) {
                acc[i][j] = __builtin_amdgcn_mfma_f32_16x16x32_bf16(ah[i], bh[j], acc[i][j], 0, 0, 0);
                acc[i][j] = __builtin_amdgcn_mfma_f32_16x16x32_bf16(ah[i], bl[j], acc[i][j], 0, 0, 0);
                acc[i][j] = __builtin_amdgcn_mfma_f32_16x16x32_bf16(al[i], bh[j], acc[i][j], 0, 0, 0);
            }
    }

#pragma unroll
    for (int i = 0; i < 4; ++i)
#pragma unroll
        for (int rr = 0; rr < 4; ++rr) {
            const int t = m0 + wm + i * 16 + q * 4 + rr;
            const float mk = (mask[b * TENC + t] == 0) ? NEG_BIG : 0.0f;
#pragma unroll
            for (int j = 0; j < 4; ++j) {
                const int u = n0 + wn + j * 16 + lr;
                C[(size_t)t * TDEC + u] = acc[i][j][rr] - mk;
            }
        }
}

__global__ __launch_bounds__(256) void softmax_kernel(float* __restrict__ S)
{
    const int b  = blockIdx.y;
    const int u0 = blockIdx.x * 16;
    const int up = threadIdx.x & 15;
    const int tg = threadIdx.x >> 4;

    float* col = S + (size_t)b * TENC * TDEC + u0;

    float m = -INFINITY, s = 0.0f;
    for (int t = tg; t < TENC; t += 16) {
        float x = col[(size_t)t * TDEC + up];
        float mn = fmaxf(m, x);
        s = s * __expf(m - mn) + __expf(x - mn);
        m = mn;
    }

    __shared__ float sm[16][17];
    __shared__ float ss[16][17];
    sm[tg][up] = m;
    ss[tg][up] = s;
    __syncthreads();

    float M = -INFINITY;
#pragma unroll
    for (int j = 0; j < 16; ++j) M = fmaxf(M, sm[j][up]);
    float sum = 0.0f;
#pragma unroll
    for (int j = 0; j < 16; ++j) sum += ss[j][up] * __expf(sm[j][up] - M);
    const float inv = 1.0f / sum;

    for (int t = tg; t < TENC; t += 16) {
        float x = col[(size_t)t * TDEC + up];
        col[(size_t)t * TDEC + up] = __expf(x - M) * inv;
    }
}

#define G2_LD 36

__global__ __launch_bounds__(256) void gemm2_mfma(
    const float* __restrict__ scores, const float* __restrict__ enc,
    float* __restrict__ context)
{
    __shared__ __align__(16) ushort_t Ah[128 * G2_LD];
    __shared__ __align__(16) ushort_t Al[128 * G2_LD];
    __shared__ __align__(16) ushort_t Bh[128 * G2_LD];
    __shared__ __align__(16) ushort_t Bl[128 * G2_LD];

    const int b  = blockIdx.z;
    const int m0 = blockIdx.y * 128;
    const int n0 = blockIdx.x * 128;
    const int tid = threadIdx.x;

    const float* S = scores + (size_t)b * TENC * TDEC;
    const float* E = enc    + (size_t)b * TENC * DIM;
    float*       C = context + (size_t)b * TDEC * DIM;

    const int lane = tid & 63;
    const int wv   = tid >> 6;
    const int wm   = (wv & 1) * 64;
    const int wn   = (wv >> 1) * 64;
    const int lr   = lane & 15;
    const int q    = lane >> 4;

    const int ul = tid & 127;
    const int th = (tid >> 7) * 16;

    f32x4 acc[4][4] = {};

    for (int k0 = 0; k0 < TENC; k0 += 32) {
        float av[16], bv[16];
#pragma unroll
        for (int i = 0; i < 4; ++i) {
            const int t = k0 + th + i * 4;
#pragma unroll
            for (int j = 0; j < 4; ++j) {
                av[i * 4 + j] = S[(size_t)(t + j) * TDEC + m0 + ul];
                bv[i * 4 + j] = E[(size_t)(t + j) * DIM + n0 + ul];
            }
        }
        __syncthreads();
#pragma unroll
        for (int i = 0; i < 4; ++i) {
            const int tt = th + i * 4;
            wr4(&Ah[ul * G2_LD + tt], &Al[ul * G2_LD + tt], &av[i * 4]);
            wr4(&Bh[ul * G2_LD + tt], &Bl[ul * G2_LD + tt], &bv[i * 4]);
        }
        __syncthreads();

        short8 ah[4], al[4], bh[4], bl[4];
#pragma unroll
        for (int i = 0; i < 4; ++i) {
            ah[i] = frag8B(&Ah[(wm + i * 16 + lr) * G2_LD + q * 8]);
            al[i] = frag8B(&Al[(wm + i * 16 + lr) * G2_LD + q * 8]);
            bh[i] = frag8B(&Bh[(wn + i * 16 + lr) * G2_LD + q * 8]);
            bl[i] = frag8B(&Bl[(wn + i * 16 + lr) * G2_LD + q * 8]);
        }
#pragma unroll
        for (int i = 0; i < 4; ++i)
#pragma unroll
            for (int j = 0; j < 4; ++j) {
                acc[i][j] = __builtin_amdgcn_mfma_f32_16x16x32_bf16(ah[i], bh[j], acc[i][j], 0, 0, 0);
                acc[i][j] = __builtin_amdgcn_mfma_f32_16x16x32_bf16(ah[i], bl[j], acc[i][j], 0, 0, 0);
                acc[i][j] = __builtin_amdgcn_mfma_f32_16x16x32_bf16(al[i], bh[j], acc[i][j], 0, 0, 0);
            }
    }

#pragma unroll
    for (int i = 0; i < 4; ++i)
#pragma unroll
        for (int rr = 0; rr < 4; ++rr) {
            const int u = m0 + wm + i * 16 + q * 4 + rr;
#pragma unroll
            for (int j = 0; j < 4; ++j) {
                const int d = n0 + wn + j * 16 + lr;
                C[(size_t)u * DIM + d] = acc[i][j][rr];
            }
        }
}

// ===========================================================================
extern "C" void kernel_launch(void* const* d_in, const int* in_sizes, int n_in,
                              void* d_out, int out_size, void* d_ws, size_t ws_size,
                              hipStream_t stream)
{
    const float* enc      = (const float*)d_in[0];
    const int*   enc_mask = (const int*)  d_in[1];
    const float* dec      = (const float*)d_in[2];

    float* context = (float*)d_out;                        // B*TDEC*DIM
    float* scores  = context + (size_t)BATCH * TDEC * DIM; // B*TENC*TDEC

    // Workspace layout (bytes). bf16 partials p0..p3 (8 MiB each) overlay
    // encH (dead after gemm1). pm/ps live in d_out's context region (dead
    // until reduce_ctx overwrites it last).
    const size_t OFF_ENC_H = 0;          // 32 MiB
    const size_t OFF_ENC_L = 33554432;   // 32 MiB
    const size_t OFF_DEC_H = 67108864;   // 8 MiB
    const size_t OFF_DEC_L = 75497472;   // 8 MiB
    const size_t OFF_ENC_T = 83886080;   // 32 MiB
    const size_t OFF_SCO_T = 117440512;  // 16 MiB
    const size_t WS_NEED   = 134217728;  // 128 MiB

    if (ws_size >= WS_NEED) {
        char* w = (char*)d_ws;
        ushort_t* encH    = (ushort_t*)(w + OFF_ENC_H);
        ushort_t* encL    = (ushort_t*)(w + OFF_ENC_L);
        ushort_t* decH    = (ushort_t*)(w + OFF_DEC_H);
        ushort_t* decL    = (ushort_t*)(w + OFF_DEC_L);
        ushort_t* encT    = (ushort_t*)(w + OFF_ENC_T);
        ushort_t* scoresT = (ushort_t*)(w + OFF_SCO_T);
        ushort_t* part0   = (ushort_t*)(w + OFF_ENC_H);             // 8 MiB
        ushort_t* part1   = (ushort_t*)(w + OFF_ENC_H + 8388608);   // 8 MiB
        ushort_t* part2   = (ushort_t*)(w + OFF_ENC_H + 16777216);  // 8 MiB
        ushort_t* part3   = (ushort_t*)(w + OFF_ENC_H + 25165824);  // 8 MiB
        float*    pm      = context;                // 256 KB, in d_out
        float*    ps      = context + 65536;        // 256 KB, in d_out

        prep_fused<<<dim3(DIM / 64, 40, BATCH), 256, 0, stream>>>(
            enc, dec, encH, encL, encT, decH, decL);

        // XCD-batch affinity: blockIdx.x = batch
        gemm1_lds<<<dim3(BATCH, TENC / 128, TDEC / 128), 256, 0, stream>>>(
            encH, encL, decH, decL, enc_mask, scores, pm, ps);

        norm_kernel<<<dim3(TENC / 64, TDEC / 64, BATCH), 256, 0, stream>>>(
            scores, pm, ps, scoresT);

        gemm2_lds<<<dim3(BATCH, 32, TDEC / 128), 256, 0, stream>>>(
            scoresT, encT, part0, part1, part2, part3);

        reduce_ctx<<<2048, 256, 0, stream>>>(part0, part1, part2, part3, context);
    } else {
        gemm1_mfma<<<dim3(TDEC / 128, TENC / 128, BATCH), 256, 0, stream>>>(
            enc, dec, enc_mask, scores);
        softmax_kernel<<<dim3(TDEC / 16, BATCH), 256, 0, stream>>>(scores);
        gemm2_mfma<<<dim3(DIM / 128, TDEC / 128, BATCH), 256, 0, stream>>>(
            scores, enc, context);
    }
}

// Round 9
// 227.243 us; speedup vs baseline: 1.0706x; 1.0262x over previous
//
#include <hip/hip_runtime.h>
#include <math.h>

#define BATCH 8
#define TENC 2048
#define TDEC 512
#define DIM 1024
#define NEG_BIG 1e20f

typedef __attribute__((ext_vector_type(8))) short short8;
typedef __attribute__((ext_vector_type(4))) float f32x4;
typedef unsigned short ushort_t;

// ---- fp32 <-> fp16 helpers (RNE via hardware cvt) --------------------------
__device__ __forceinline__ ushort_t f16bits(float x) {
    union { _Float16 h; ushort_t u; } cv;
    cv.h = (_Float16)x;
    return cv.u;
}
__device__ __forceinline__ float f16val(ushort_t u) {
    union { _Float16 h; ushort_t u; } cv;
    cv.u = u;
    return (float)cv.h;
}

// ---- fp32 -> bf16 helpers (fallback path only) -----------------------------
__device__ __forceinline__ unsigned int bf16rn(float x) {
    unsigned int u = __float_as_uint(x);
    return (u + 0x7FFFu + ((u >> 16) & 1u)) >> 16;
}
__device__ __forceinline__ float bf16f(unsigned int b) {
    return __uint_as_float(b << 16);
}
__device__ __forceinline__ void split2(float x, unsigned int& h, unsigned int& l) {
    h = bf16rn(x);
    l = bf16rn(x - bf16f(h));
}

// async global -> LDS, 16B/lane, wave-uniform LDS base
#define GLOAD16(g, l)                                                        \
    __builtin_amdgcn_global_load_lds(                                        \
        (const __attribute__((address_space(1))) unsigned int*)(g),          \
        (__attribute__((address_space(3))) unsigned int*)(l), 16, 0, 0)

// Tiled ("fragment-linear") operand layout (verified r6: 0 conflicts, full
// coalescing): matrix [ROWS][K] -> 16x32 tiles of 512 shorts (1 KB);
// tile idx = (row>>4)*(K/32)+(k>>5); elem(r, 8q+j) at q*128 + r*8 + j.
__device__ __forceinline__ size_t tiled_off(int row, int k, int ntK) {
    return ((size_t)(row >> 4) * ntK + (k >> 5)) * 512
         + ((k >> 3) & 3) * 128 + (row & 15) * 8;
}

// ===========================================================================
// PRIMARY PATH (fp16, needs 128 MiB workspace)
// ===========================================================================

// ---------------------------------------------------------------------------
// prep_fused: blockIdx.y < 32  -> enc tile: encH fp16 tiled (rows=t,K=d)
//                                  + encT fp16 tiled (rows=d,K=t).
//             blockIdx.y >= 32 -> dec tile: decH/decL fp16 split, tiled.
// Asymmetric split: enc hi-only (fp16), dec split hi+lo (fp16 each) -- the
// dropped eps_enc*dec term is ~2^-12 relative (safe; see r9 analysis).
// ---------------------------------------------------------------------------
__global__ __launch_bounds__(256) void prep_fused(
    const float* __restrict__ enc, const float* __restrict__ dec,
    ushort_t* __restrict__ encH, ushort_t* __restrict__ encT,
    ushort_t* __restrict__ decH, ushort_t* __restrict__ decL)
{
    __shared__ ushort_t T[64][72];   // [d][t] (enc branch only)

    const int b   = blockIdx.z;
    const int d0  = blockIdx.x * 64;
    const int tid = threadIdx.x;

    if (blockIdx.y < 32) {
        const int t0 = blockIdx.y * 64;
        const float* E = enc + (size_t)b * TENC * DIM;
        const size_t bofs1 = (size_t)b * TENC * DIM;
        const size_t bofs2 = (size_t)b * DIM * TENC;

        const int ltr = tid >> 2;          // 0..63 t-row
#pragma unroll
        for (int it = 0; it < 2; ++it) {
            const int c  = (tid & 3) + it * 4;   // chunk of 8 d
            const int gt = t0 + ltr;
            const int gd = d0 + c * 8;
            float4 x0 = *(const float4*)&E[(size_t)gt * DIM + gd];
            float4 x1 = *(const float4*)&E[(size_t)gt * DIM + gd + 4];
            float xs[8] = {x0.x, x0.y, x0.z, x0.w, x1.x, x1.y, x1.z, x1.w};
            short8 hv;
#pragma unroll
            for (int j = 0; j < 8; ++j) hv[j] = (short)f16bits(xs[j]);
            *(short8*)&encH[bofs1 + tiled_off(gt, gd, DIM / 32)] = hv;
#pragma unroll
            for (int j = 0; j < 8; ++j) T[c * 8 + j][ltr] = (ushort_t)hv[j];
        }
        __syncthreads();

        const int dr = tid >> 2;           // 0..63 d-row
#pragma unroll
        for (int it = 0; it < 2; ++it) {
            const int tc = (tid & 3) + it * 4;   // chunk of 8 t
            short8 v = *(const short8*)&T[dr][tc * 8];
            *(short8*)&encT[bofs2 + tiled_off(d0 + dr, t0 + tc * 8, TENC / 32)] = v;
        }
    } else {
        const int u0 = (blockIdx.y - 32) * 64;
        const float* D = dec + (size_t)b * TDEC * DIM;
        const size_t bofs = (size_t)b * TDEC * DIM;

        const int lur = tid >> 2;          // 0..63 u-row
#pragma unroll
        for (int it = 0; it < 2; ++it) {
            const int c  = (tid & 3) + it * 4;
            const int gu = u0 + lur;
            const int gd = d0 + c * 8;
            float4 x0 = *(const float4*)&D[(size_t)gu * DIM + gd];
            float4 x1 = *(const float4*)&D[(size_t)gu * DIM + gd + 4];
            float xs[8] = {x0.x, x0.y, x0.z, x0.w, x1.x, x1.y, x1.z, x1.w};
            short8 hv, lv;
#pragma unroll
            for (int j = 0; j < 8; ++j) {
                ushort_t h = f16bits(xs[j]);
                hv[j] = (short)h;
                lv[j] = (short)f16bits(xs[j] - f16val(h));
            }
            const size_t off = bofs + tiled_off(gu, gd, DIM / 32);
            *(short8*)&decH[off] = hv;
            *(short8*)&decL[off] = lv;
        }
    }
}

// ---------------------------------------------------------------------------
// gemm1_lds: p16[b,t,u] = exp(raw - M_tile), fp16; raw = encH*(decH+decL)
// (2 MFMA/pair). XCD-batch affinity (x=batch). Fused full-tile column max,
// exp, and (M_tile, sum) partial stats -> pm/ps (in d_out context region).
// No fp32 raw write -- norm rescales p16.
// ---------------------------------------------------------------------------
__global__ __launch_bounds__(256) void gemm1_lds(
    const ushort_t* __restrict__ encH, const ushort_t* __restrict__ decH,
    const ushort_t* __restrict__ decL, const int* __restrict__ mask,
    ushort_t* __restrict__ p16, float* __restrict__ pm, float* __restrict__ ps)
{
    __shared__ __align__(16) ushort_t Ah[128 * 32];
    __shared__ __align__(16) ushort_t Bh[128 * 32];
    __shared__ __align__(16) ushort_t Bl[128 * 32];
    __shared__ float smx[4][68];
    __shared__ float ssx[4][68];

    const int b  = blockIdx.x;         // batch -> XCD affinity
    const int m0 = blockIdx.y * 128;   // t
    const int n0 = blockIdx.z * 128;   // u
    const int tid = threadIdx.x;

    const int lane = tid & 63;
    const int w    = tid >> 6;
    const int wm   = (w & 1) * 64;
    const int wn   = (w >> 1) * 64;
    const int lr   = lane & 15;
    const int q    = lane >> 4;
    const int l8   = lane * 8;

    const int fa = wm * 32 + q * 128 + lr * 8;
    const int fb = wn * 32 + q * 128 + lr * 8;

    const ushort_t* AH = encH + (size_t)b * TENC * DIM;
    const ushort_t* BH = decH + (size_t)b * TDEC * DIM;
    const ushort_t* BL = decL + (size_t)b * TDEC * DIM;
    ushort_t* P = p16 + (size_t)b * TENC * TDEC;

    f32x4 acc[4][4] = {};

    for (int k0 = 0; k0 < DIM; k0 += 32) {
        __syncthreads();
#pragma unroll
        for (int q2 = 0; q2 < 2; ++q2) {
            const int rg = w * 2 + q2;
            const size_t tA = ((size_t)((m0 >> 4) + rg) * (DIM / 32) + (k0 >> 5)) * 512 + l8;
            const size_t tB = ((size_t)((n0 >> 4) + rg) * (DIM / 32) + (k0 >> 5)) * 512 + l8;
            GLOAD16(AH + tA, &Ah[rg * 512]);
            GLOAD16(BH + tB, &Bh[rg * 512]);
            GLOAD16(BL + tB, &Bl[rg * 512]);
        }
        __syncthreads();

        short8 ah[4], bh[4], bl[4];
#pragma unroll
        for (int i = 0; i < 4; ++i) {
            ah[i] = *(const short8*)&Ah[fa + i * 512];
            bh[i] = *(const short8*)&Bh[fb + i * 512];
            bl[i] = *(const short8*)&Bl[fb + i * 512];
        }
#pragma unroll
        for (int i = 0; i < 4; ++i)
#pragma unroll
            for (int j = 0; j < 4; ++j) {
                acc[i][j] = __builtin_amdgcn_mfma_f32_16x16x32_f16(ah[i], bh[j], acc[i][j], 0, 0, 0);
                acc[i][j] = __builtin_amdgcn_mfma_f32_16x16x32_f16(ah[i], bl[j], acc[i][j], 0, 0, 0);
            }
    }

    float mkv[4][4];
#pragma unroll
    for (int i = 0; i < 4; ++i)
#pragma unroll
        for (int rr = 0; rr < 4; ++rr) {
            const int t = m0 + wm + i * 16 + q * 4 + rr;
            mkv[i][rr] = (mask[b * TENC + t] == 0) ? NEG_BIG : 0.0f;
        }

    // pass A: per-lane column max over this lane's 16 rows
    float cm[4] = {-INFINITY, -INFINITY, -INFINITY, -INFINITY};
#pragma unroll
    for (int i = 0; i < 4; ++i)
#pragma unroll
        for (int rr = 0; rr < 4; ++rr)
#pragma unroll
            for (int j = 0; j < 4; ++j)
                cm[j] = fmaxf(cm[j], acc[i][j][rr] - mkv[i][rr]);
    // combine across the 4 q-groups (lanes lr, lr+16, lr+32, lr+48)
#pragma unroll
    for (int j = 0; j < 4; ++j) {
        cm[j] = fmaxf(cm[j], __shfl_xor(cm[j], 16, 64));
        cm[j] = fmaxf(cm[j], __shfl_xor(cm[j], 32, 64));
    }
    // cross-wave max: waves (w, w^1) cover the same 64 columns (wm 0/64)
    if (q == 0) {
#pragma unroll
        for (int j = 0; j < 4; ++j) smx[w][j * 16 + lr] = cm[j];
    }
    __syncthreads();
    float M[4];
#pragma unroll
    for (int j = 0; j < 4; ++j)
        M[j] = fmaxf(smx[w][j * 16 + lr], smx[w ^ 1][j * 16 + lr]);

    // pass B: p = exp(v - M), write fp16, accumulate sum (common M: no rescale)
    float cs[4] = {0.f, 0.f, 0.f, 0.f};
#pragma unroll
    for (int i = 0; i < 4; ++i)
#pragma unroll
        for (int rr = 0; rr < 4; ++rr) {
            const int t = m0 + wm + i * 16 + q * 4 + rr;
#pragma unroll
            for (int j = 0; j < 4; ++j) {
                const int u = n0 + wn + j * 16 + lr;
                const float p = __expf(acc[i][j][rr] - mkv[i][rr] - M[j]);
                cs[j] += p;
                P[(size_t)t * TDEC + u] = f16bits(p);
            }
        }
#pragma unroll
    for (int j = 0; j < 4; ++j) {
        cs[j] += __shfl_xor(cs[j], 16, 64);
        cs[j] += __shfl_xor(cs[j], 32, 64);
    }
    if (q == 0) {
#pragma unroll
        for (int j = 0; j < 4; ++j) ssx[w][j * 16 + lr] = cs[j];
    }
    __syncthreads();
    if (tid < 128) {
        const int col = tid;
        const int wp  = (col >> 6) * 2;
        const int ci  = col & 63;
        const float Mf = fmaxf(smx[wp][ci], smx[wp + 1][ci]);
        const float Sf = ssx[wp][ci] + ssx[wp + 1][ci];
        const int idx = b * TDEC + n0 + col;
        const int tb  = m0 >> 7;
        pm[(size_t)tb * (BATCH * TDEC) + idx] = Mf;
        ps[(size_t)tb * (BATCH * TDEC) + idx] = Sf;
    }
}

// ---------------------------------------------------------------------------
// norm: exp-free. scores = p16 * w,  w[u] = exp(M_tb - M_global)/S_global.
// Writes scores fp32 (d_out) + scoresT fp16 tiled (rows=u, K=t).
// Each block covers one tb (t0 aligned to 64 -> tb = t0>>7 unique).
// ---------------------------------------------------------------------------
__global__ __launch_bounds__(256) void norm_kernel(
    const ushort_t* __restrict__ p16, float* __restrict__ scores,
    const float* __restrict__ pm, const float* __restrict__ ps,
    ushort_t* __restrict__ scoresT)
{
    __shared__ ushort_t T[64][72];   // [u][t]
    __shared__ float cW[64];

    const int b  = blockIdx.z;
    const int t0 = blockIdx.x * 64;
    const int u0 = blockIdx.y * 64;
    const int tb = t0 >> 7;
    const int tid = threadIdx.x;

    if (tid < 64) {
        const int idx = b * TDEC + u0 + tid;
        float M = -INFINITY;
#pragma unroll
        for (int z = 0; z < 16; ++z)
            M = fmaxf(M, pm[(size_t)z * (BATCH * TDEC) + idx]);
        float s = 0.0f;
#pragma unroll
        for (int z = 0; z < 16; ++z)
            s += ps[(size_t)z * (BATCH * TDEC) + idx] *
                 __expf(pm[(size_t)z * (BATCH * TDEC) + idx] - M);
        cW[tid] = __expf(pm[(size_t)tb * (BATCH * TDEC) + idx] - M) / s;
    }
    __syncthreads();

    const int tr  = tid >> 4;
    const int ucl = (tid & 15) * 4;

    const float w0 = cW[ucl + 0], w1 = cW[ucl + 1];
    const float w2 = cW[ucl + 2], w3 = cW[ucl + 3];

    const ushort_t* Pb = p16 + (size_t)b * TENC * TDEC;
    float* Sb = scores + (size_t)b * TENC * TDEC;

#pragma unroll
    for (int i = 0; i < 4; ++i) {
        const int t = t0 + tr + 16 * i;
        ushort4 pv = *(const ushort4*)&Pb[(size_t)t * TDEC + u0 + ucl];
        float4 sc;
        sc.x = f16val(pv.x) * w0;
        sc.y = f16val(pv.y) * w1;
        sc.z = f16val(pv.z) * w2;
        sc.w = f16val(pv.w) * w3;
        *(float4*)&Sb[(size_t)t * TDEC + u0 + ucl] = sc;
        const int tloc = tr + 16 * i;
        T[ucl + 0][tloc] = f16bits(sc.x);
        T[ucl + 1][tloc] = f16bits(sc.y);
        T[ucl + 2][tloc] = f16bits(sc.z);
        T[ucl + 3][tloc] = f16bits(sc.w);
    }
    __syncthreads();

    const size_t bofs = (size_t)b * TDEC * TENC;
    const int ur = tid >> 2;
#pragma unroll
    for (int it = 0; it < 2; ++it) {
        const int tc = (tid & 3) + it * 4;
        short8 v = *(const short8*)&T[ur][tc * 8];
        *(short8*)&scoresT[bofs + tiled_off(u0 + ur, t0 + tc * 8, TENC / 32)] = v;
    }
}

// ---------------------------------------------------------------------------
// gemm2_lds: fp16 partial[ks] = scoresT*encT^T k-slice. 128u x 256d tile
// (MFMA:staging 5.3/KB), split-K=4, XCD-batch affinity.
// Grid (BATCH, 16, 4): y = ks*4 + d-tile, z = u-tile. 512 blocks.
// ---------------------------------------------------------------------------
__global__ __launch_bounds__(256) void gemm2_lds(
    const ushort_t* __restrict__ scoresT, const ushort_t* __restrict__ encT,
    ushort_t* __restrict__ p0, ushort_t* __restrict__ p1,
    ushort_t* __restrict__ p2, ushort_t* __restrict__ p3)
{
    __shared__ __align__(16) ushort_t Ah[128 * 32];   //  8 KB
    __shared__ __align__(16) ushort_t Bh[256 * 32];   // 16 KB

    const int b  = blockIdx.x;             // batch -> XCD affinity
    const int ks = blockIdx.y >> 2;
    const int n0 = (blockIdx.y & 3) * 256; // d
    const int m0 = blockIdx.z * 128;       // u
    const int tid = threadIdx.x;

    const int lane = tid & 63;
    const int w    = tid >> 6;
    const int wm   = (w & 1) * 64;
    const int wn   = (w >> 1) * 128;
    const int lr   = lane & 15;
    const int q    = lane >> 4;
    const int l8   = lane * 8;

    const int fa = wm * 32 + q * 128 + lr * 8;
    const int fb = wn * 32 + q * 128 + lr * 8;

    const ushort_t* A = scoresT + (size_t)b * TDEC * TENC;
    const ushort_t* B = encT    + (size_t)b * DIM * TENC;
    ushort_t* Psel = ks == 0 ? p0 : (ks == 1 ? p1 : (ks == 2 ? p2 : p3));
    ushort_t* P = Psel + (size_t)b * TDEC * DIM;

    const int kbeg = ks * (TENC / 4);
    const int kend = kbeg + TENC / 4;

    f32x4 acc[4][8] = {};

    for (int k0 = kbeg; k0 < kend; k0 += 32) {
        __syncthreads();
#pragma unroll
        for (int q2 = 0; q2 < 2; ++q2) {
            const int rg = w * 2 + q2;
            const size_t tA = ((size_t)((m0 >> 4) + rg) * (TENC / 32) + (k0 >> 5)) * 512 + l8;
            GLOAD16(A + tA, &Ah[rg * 512]);
        }
#pragma unroll
        for (int q2 = 0; q2 < 4; ++q2) {
            const int rg = w * 4 + q2;
            const size_t tB = ((size_t)((n0 >> 4) + rg) * (TENC / 32) + (k0 >> 5)) * 512 + l8;
            GLOAD16(B + tB, &Bh[rg * 512]);
        }
        __syncthreads();

        short8 av[4], bv[8];
#pragma unroll
        for (int i = 0; i < 4; ++i) av[i] = *(const short8*)&Ah[fa + i * 512];
#pragma unroll
        for (int j = 0; j < 8; ++j) bv[j] = *(const short8*)&Bh[fb + j * 512];
#pragma unroll
        for (int i = 0; i < 4; ++i)
#pragma unroll
            for (int j = 0; j < 8; ++j)
                acc[i][j] = __builtin_amdgcn_mfma_f32_16x16x32_f16(av[i], bv[j], acc[i][j], 0, 0, 0);
    }

#pragma unroll
    for (int i = 0; i < 4; ++i)
#pragma unroll
        for (int rr = 0; rr < 4; ++rr) {
            const int u = m0 + wm + i * 16 + q * 4 + rr;
#pragma unroll
            for (int j = 0; j < 8; ++j) {
                const int d = n0 + wn + j * 16 + lr;
                P[(size_t)u * DIM + d] = f16bits(acc[i][j][rr]);
            }
        }
}

// ---------------------------------------------------------------------------
// reduce_ctx: context = sum of 4 fp16 partials (fp32 accumulate). Grid 2048.
// ---------------------------------------------------------------------------
__global__ __launch_bounds__(256) void reduce_ctx(
    const ushort_t* __restrict__ p0, const ushort_t* __restrict__ p1,
    const ushort_t* __restrict__ p2, const ushort_t* __restrict__ p3,
    float* __restrict__ ctx)
{
    const size_t i8 = ((size_t)blockIdx.x * 256 + threadIdx.x) * 8;
    short8 a = *(const short8*)(p0 + i8);
    short8 b = *(const short8*)(p1 + i8);
    short8 c = *(const short8*)(p2 + i8);
    short8 d = *(const short8*)(p3 + i8);
    float o[8];
#pragma unroll
    for (int j = 0; j < 8; ++j)
        o[j] = f16val((ushort_t)a[j]) + f16val((ushort_t)b[j])
             + f16val((ushort_t)c[j]) + f16val((ushort_t)d[j]);
    *(float4*)(ctx + i8)     = make_float4(o[0], o[1], o[2], o[3]);
    *(float4*)(ctx + i8 + 4) = make_float4(o[4], o[5], o[6], o[7]);
}

// ===========================================================================
// FALLBACK PATH (round-2 proven kernels; used if workspace is too small)
// ===========================================================================

__device__ __forceinline__ void store8(ushort_t* ph, ushort_t* pl,
                                       float4 x0, float4 x1) {
    float xs[8] = {x0.x, x0.y, x0.z, x0.w, x1.x, x1.y, x1.z, x1.w};
    short8 hv, lv;
#pragma unroll
    for (int i = 0; i < 8; ++i) {
        unsigned int h, l;
        split2(xs[i], h, l);
        hv[i] = (short)h;
        lv[i] = (short)l;
    }
    *(short8*)ph = hv;
    *(short8*)pl = lv;
}

__device__ __forceinline__ void wr4(ushort_t* ph, ushort_t* pl, const float* x) {
    unsigned int h[4], l[4];
#pragma unroll
    for (int i = 0; i < 4; ++i) split2(x[i], h[i], l[i]);
    *(uint2*)ph = make_uint2(h[0] | (h[1] << 16), h[2] | (h[3] << 16));
    *(uint2*)pl = make_uint2(l[0] | (l[1] << 16), l[2] | (l[3] << 16));
}

__device__ __forceinline__ short8 frag8B(const ushort_t* p) {
    union { short8 v; uint2 u[2]; } f;
    f.u[0] = *(const uint2*)p;
    f.u[1] = *(const uint2*)(p + 4);
    return f.v;
}

__global__ __launch_bounds__(256) void gemm1_mfma(
    const float* __restrict__ enc, const float* __restrict__ dec,
    const int* __restrict__ mask, float* __restrict__ raw)
{
    __shared__ __align__(16) ushort_t Ah[128 * 32];
    __shared__ __align__(16) ushort_t Al[128 * 32];
    __shared__ __align__(16) ushort_t Bh[128 * 32];
    __shared__ __align__(16) ushort_t Bl[128 * 32];

    const int b  = blockIdx.z;
    const int m0 = blockIdx.y * 128;
    const int n0 = blockIdx.x * 128;
    const int tid = threadIdx.x;

    const float* A  = enc + (size_t)b * TENC * DIM;
    const float* Bg = dec + (size_t)b * TDEC * DIM;
    float*       C  = raw + (size_t)b * TENC * TDEC;

    const int lane = tid & 63;
    const int wv   = tid >> 6;
    const int wm   = (wv & 1) * 64;
    const int wn   = (wv >> 1) * 64;
    const int lr   = lane & 15;
    const int q    = lane >> 4;

    const int r0 = tid >> 2;
    const int c8 = (tid & 3) * 8;

    f32x4 acc[4][4] = {};

    for (int k0 = 0; k0 < DIM; k0 += 32) {
        const float* pa0 = A  + (size_t)(m0 + r0) * DIM + k0 + c8;
        const float* pa1 = A  + (size_t)(m0 + r0 + 64) * DIM + k0 + c8;
        const float* pb0 = Bg + (size_t)(n0 + r0) * DIM + k0 + c8;
        const float* pb1 = Bg + (size_t)(n0 + r0 + 64) * DIM + k0 + c8;
        float4 a0 = *(const float4*)pa0, a0b = *(const float4*)(pa0 + 4);
        float4 a1 = *(const float4*)pa1, a1b = *(const float4*)(pa1 + 4);
        float4 b0 = *(const float4*)pb0, b0b = *(const float4*)(pb0 + 4);
        float4 b1 = *(const float4*)pb1, b1b = *(const float4*)(pb1 + 4);

        __syncthreads();
        store8(&Ah[r0 * 32 + c8],        &Al[r0 * 32 + c8],        a0, a0b);
        store8(&Ah[(r0 + 64) * 32 + c8], &Al[(r0 + 64) * 32 + c8], a1, a1b);
        store8(&Bh[r0 * 32 + c8],        &Bl[r0 * 32 + c8],        b0, b0b);
        store8(&Bh[(r0 + 64) * 32 + c8], &Bl[(r0 + 64) * 32 + c8], b1, b1b);
        __syncthreads();

        short8 ah[4], al[4], bh[4], bl[4];
#pragma unroll
        for (int i = 0; i < 4; ++i) {
            ah[i] = *(const short8*)&Ah[(wm + i * 16 + lr) * 32 + q * 8];
            al[i] = *(const short8*)&Al[(wm + i * 16 + lr) * 32 + q * 8];
            bh[i] = *(const short8*)&Bh[(wn + i * 16 + lr) * 32 + q * 8];
            bl[i] = *(const short8*)&Bl[(wn + i * 16 + lr) * 32 + q * 8];
        }
#pragma unroll
        for (int i = 0; i < 4; ++i)
#pragma unroll
            for (int j = 0; j < 4; ++j) {
                acc[i][j] = __builtin_amdgcn_mfma_f32_16x16x32_bf16(ah[i], bh[j], acc[i][j], 0, 0, 0);
                acc[i][j] = __builtin_amdgcn_mfma_f32_16x16x32_bf16(ah[i], bl[j], acc[i][j], 0, 0, 0);
                acc[i][j] = __builtin_amdgcn_mfma_f32_16x16x32_bf16(al[i], bh[j], acc[i][j], 0, 0, 0);
            }
    }

#pragma unroll
    for (int i = 0; i < 4; ++i)
#pragma unroll
        for (int rr = 0; rr < 4; ++rr) {
            const int t = m0 + wm + i * 16 + q * 4 + rr;
            const float mk = (mask[b * TENC + t] == 0) ? NEG_BIG : 0.0f;
#pragma unroll
            for (int j = 0; j < 4; ++j) {
                const int u = n0 + wn + j * 16 + lr;
                C[(size_t)t * TDEC + u] = acc[i][j][rr] - mk;
            }
        }
}

__global__ __launch_bounds__(256) void softmax_kernel(float* __restrict__ S)
{
    const int b  = blockIdx.y;
    const int u0 = blockIdx.x * 16;
    const int up = threadIdx.x & 15;
    const int tg = threadIdx.x >> 4;

    float* col = S + (size_t)b * TENC * TDEC + u0;

    float m = -INFINITY, s = 0.0f;
    for (int t = tg; t < TENC; t += 16) {
        float x = col[(size_t)t * TDEC + up];
        float mn = fmaxf(m, x);
        s = s * __expf(m - mn) + __expf(x - mn);
        m = mn;
    }

    __shared__ float sm[16][17];
    __shared__ float ss[16][17];
    sm[tg][up] = m;
    ss[tg][up] = s;
    __syncthreads();

    float M = -INFINITY;
#pragma unroll
    for (int j = 0; j < 16; ++j) M = fmaxf(M, sm[j][up]);
    float sum = 0.0f;
#pragma unroll
    for (int j = 0; j < 16; ++j) sum += ss[j][up] * __expf(sm[j][up] - M);
    const float inv = 1.0f / sum;

    for (int t = tg; t < TENC; t += 16) {
        float x = col[(size_t)t * TDEC + up];
        col[(size_t)t * TDEC + up] = __expf(x - M) * inv;
    }
}

#define G2_LD 36

__global__ __launch_bounds__(256) void gemm2_mfma(
    const float* __restrict__ scores, const float* __restrict__ enc,
    float* __restrict__ context)
{
    __shared__ __align__(16) ushort_t Ah[128 * G2_LD];
    __shared__ __align__(16) ushort_t Al[128 * G2_LD];
    __shared__ __align__(16) ushort_t Bh[128 * G2_LD];
    __shared__ __align__(16) ushort_t Bl[128 * G2_LD];

    const int b  = blockIdx.z;
    const int m0 = blockIdx.y * 128;
    const int n0 = blockIdx.x * 128;
    const int tid = threadIdx.x;

    const float* S = scores + (size_t)b * TENC * TDEC;
    const float* E = enc    + (size_t)b * TENC * DIM;
    float*       C = context + (size_t)b * TDEC * DIM;

    const int lane = tid & 63;
    const int wv   = tid >> 6;
    const int wm   = (wv & 1) * 64;
    const int wn   = (wv >> 1) * 64;
    const int lr   = lane & 15;
    const int q    = lane >> 4;

    const int ul = tid & 127;
    const int th = (tid >> 7) * 16;

    f32x4 acc[4][4] = {};

    for (int k0 = 0; k0 < TENC; k0 += 32) {
        float av[16], bv[16];
#pragma unroll
        for (int i = 0; i < 4; ++i) {
            const int t = k0 + th + i * 4;
#pragma unroll
            for (int j = 0; j < 4; ++j) {
                av[i * 4 + j] = S[(size_t)(t + j) * TDEC + m0 + ul];
                bv[i * 4 + j] = E[(size_t)(t + j) * DIM + n0 + ul];
            }
        }
        __syncthreads();
#pragma unroll
        for (int i = 0; i < 4; ++i) {
            const int tt = th + i * 4;
            wr4(&Ah[ul * G2_LD + tt], &Al[ul * G2_LD + tt], &av[i * 4]);
            wr4(&Bh[ul * G2_LD + tt], &Bl[ul * G2_LD + tt], &bv[i * 4]);
        }
        __syncthreads();

        short8 ah[4], al[4], bh[4], bl[4];
#pragma unroll
        for (int i = 0; i < 4; ++i) {
            ah[i] = frag8B(&Ah[(wm + i * 16 + lr) * G2_LD + q * 8]);
            al[i] = frag8B(&Al[(wm + i * 16 + lr) * G2_LD + q * 8]);
            bh[i] = frag8B(&Bh[(wn + i * 16 + lr) * G2_LD + q * 8]);
            bl[i] = frag8B(&Bl[(wn + i * 16 + lr) * G2_LD + q * 8]);
        }
#pragma unroll
        for (int i = 0; i < 4; ++i)
#pragma unroll
            for (int j = 0; j < 4; ++j) {
                acc[i][j] = __builtin_amdgcn_mfma_f32_16x16x32_bf16(ah[i], bh[j], acc[i][j], 0, 0, 0);
                acc[i][j] = __builtin_amdgcn_mfma_f32_16x16x32_bf16(ah[i], bl[j], acc[i][j], 0, 0, 0);
                acc[i][j] = __builtin_amdgcn_mfma_f32_16x16x32_bf16(al[i], bh[j], acc[i][j], 0, 0, 0);
            }
    }

#pragma unroll
    for (int i = 0; i < 4; ++i)
#pragma unroll
        for (int rr = 0; rr < 4; ++rr) {
            const int u = m0 + wm + i * 16 + q * 4 + rr;
#pragma unroll
            for (int j = 0; j < 4; ++j) {
                const int d = n0 + wn + j * 16 + lr;
                C[(size_t)u * DIM + d] = acc[i][j][rr];
            }
        }
}

// ===========================================================================
extern "C" void kernel_launch(void* const* d_in, const int* in_sizes, int n_in,
                              void* d_out, int out_size, void* d_ws, size_t ws_size,
                              hipStream_t stream)
{
    const float* enc      = (const float*)d_in[0];
    const int*   enc_mask = (const int*)  d_in[1];
    const float* dec      = (const float*)d_in[2];

    float* context = (float*)d_out;                        // B*TDEC*DIM
    float* scores  = context + (size_t)BATCH * TDEC * DIM; // B*TENC*TDEC

    // Workspace layout (bytes), 128 MiB total:
    //   [  0M, 32M)  encH fp16 tiled        (dead after gemm1 -> fp16 partials)
    //   [ 32M, 48M)  p16 (exp(raw-Mtile))   written by gemm1, read by norm
    //   [ 48M, 64M)  spare
    //   [ 64M, 72M)  decH    [ 72M, 80M) decL
    //   [ 80M,112M)  encT fp16 tiled
    //   [112M,128M)  scoresT fp16 tiled
    // pm/ps (512 KB) live in d_out's context region (overwritten last by
    // reduce_ctx).
    const size_t OFF_ENC_H = 0;
    const size_t OFF_P16   = 33554432;
    const size_t OFF_DEC_H = 67108864;
    const size_t OFF_DEC_L = 75497472;
    const size_t OFF_ENC_T = 83886080;
    const size_t OFF_SCO_T = 117440512;
    const size_t WS_NEED   = 134217728;

    if (ws_size >= WS_NEED) {
        char* w = (char*)d_ws;
        ushort_t* encH    = (ushort_t*)(w + OFF_ENC_H);
        ushort_t* p16     = (ushort_t*)(w + OFF_P16);
        ushort_t* decH    = (ushort_t*)(w + OFF_DEC_H);
        ushort_t* decL    = (ushort_t*)(w + OFF_DEC_L);
        ushort_t* encT    = (ushort_t*)(w + OFF_ENC_T);
        ushort_t* scoresT = (ushort_t*)(w + OFF_SCO_T);
        ushort_t* part0   = (ushort_t*)(w + OFF_ENC_H);             // 8 MiB
        ushort_t* part1   = (ushort_t*)(w + OFF_ENC_H + 8388608);
        ushort_t* part2   = (ushort_t*)(w + OFF_ENC_H + 16777216);
        ushort_t* part3   = (ushort_t*)(w + OFF_ENC_H + 25165824);
        float*    pm      = context;                // 256 KB, in d_out
        float*    ps      = context + 65536;        // 256 KB, in d_out

        prep_fused<<<dim3(DIM / 64, 40, BATCH), 256, 0, stream>>>(
            enc, dec, encH, encT, decH, decL);

        gemm1_lds<<<dim3(BATCH, TENC / 128, TDEC / 128), 256, 0, stream>>>(
            encH, decH, decL, enc_mask, p16, pm, ps);

        norm_kernel<<<dim3(TENC / 64, TDEC / 64, BATCH), 256, 0, stream>>>(
            p16, scores, pm, ps, scoresT);

        gemm2_lds<<<dim3(BATCH, 16, TDEC / 128), 256, 0, stream>>>(
            scoresT, encT, part0, part1, part2, part3);

        reduce_ctx<<<2048, 256, 0, stream>>>(part0, part1, part2, part3, context);
    } else {
        gemm1_mfma<<<dim3(TDEC / 128, TENC / 128, BATCH), 256, 0, stream>>>(
            enc, dec, enc_mask, scores);
        softmax_kernel<<<dim3(TDEC / 16, BATCH), 256, 0, stream>>>(scores);
        gemm2_mfma<<<dim3(DIM / 128, TDEC / 128, BATCH), 256, 0, stream>>>(
            scores, enc, context);
    }
}

// Round 10
// 224.743 us; speedup vs baseline: 1.0825x; 1.0111x over previous
//
#include <hip/hip_runtime.h>
#include <math.h>

#define BATCH 8
#define TENC 2048
#define TDEC 512
#define DIM 1024
#define NEG_BIG 1e20f

typedef __attribute__((ext_vector_type(8))) short short8;
typedef __attribute__((ext_vector_type(4))) float f32x4;
typedef unsigned short ushort_t;

// ---- fp32 <-> fp16 helpers (RNE via hardware cvt) --------------------------
__device__ __forceinline__ ushort_t f16bits(float x) {
    union { _Float16 h; ushort_t u; } cv;
    cv.h = (_Float16)x;
    return cv.u;
}
__device__ __forceinline__ float f16val(ushort_t u) {
    union { _Float16 h; ushort_t u; } cv;
    cv.u = u;
    return (float)cv.h;
}

// ---- fp32 -> bf16 helpers (fallback path only) -----------------------------
__device__ __forceinline__ unsigned int bf16rn(float x) {
    unsigned int u = __float_as_uint(x);
    return (u + 0x7FFFu + ((u >> 16) & 1u)) >> 16;
}
__device__ __forceinline__ float bf16f(unsigned int b) {
    return __uint_as_float(b << 16);
}
__device__ __forceinline__ void split2(float x, unsigned int& h, unsigned int& l) {
    h = bf16rn(x);
    l = bf16rn(x - bf16f(h));
}

// async global -> LDS, 16B/lane, wave-uniform LDS base
#define GLOAD16(g, l)                                                        \
    __builtin_amdgcn_global_load_lds(                                        \
        (const __attribute__((address_space(1))) unsigned int*)(g),          \
        (__attribute__((address_space(3))) unsigned int*)(l), 16, 0, 0)

// Tiled ("fragment-linear") operand layout (verified r6: 0 conflicts, full
// coalescing): matrix [ROWS][K] -> 16x32 tiles of 512 shorts (1 KB);
// tile idx = (row>>4)*(K/32)+(k>>5); elem(r, 8q+j) at q*128 + r*8 + j.
__device__ __forceinline__ size_t tiled_off(int row, int k, int ntK) {
    return ((size_t)(row >> 4) * ntK + (k >> 5)) * 512
         + ((k >> 3) & 3) * 128 + (row & 15) * 8;
}

// ===========================================================================
// PRIMARY PATH (fp16, needs 128 MiB workspace)
// ===========================================================================

// ---------------------------------------------------------------------------
// prep_fused: blockIdx.y < 32  -> enc tile: encH fp16 tiled (rows=t,K=d)
//                                  + encT fp16 tiled (rows=d,K=t).
//             blockIdx.y >= 32 -> dec tile: decH/decL fp16 split, tiled.
// Asymmetric split: enc hi-only (fp16), dec split hi+lo (fp16 each) -- the
// dropped eps_enc*dec term is ~2^-12 relative (verified r9: absmax 0.037).
// ---------------------------------------------------------------------------
__global__ __launch_bounds__(256) void prep_fused(
    const float* __restrict__ enc, const float* __restrict__ dec,
    ushort_t* __restrict__ encH, ushort_t* __restrict__ encT,
    ushort_t* __restrict__ decH, ushort_t* __restrict__ decL)
{
    __shared__ ushort_t T[64][72];   // [d][t] (enc branch only)

    const int b   = blockIdx.z;
    const int d0  = blockIdx.x * 64;
    const int tid = threadIdx.x;

    if (blockIdx.y < 32) {
        const int t0 = blockIdx.y * 64;
        const float* E = enc + (size_t)b * TENC * DIM;
        const size_t bofs1 = (size_t)b * TENC * DIM;
        const size_t bofs2 = (size_t)b * DIM * TENC;

        const int ltr = tid >> 2;          // 0..63 t-row
#pragma unroll
        for (int it = 0; it < 2; ++it) {
            const int c  = (tid & 3) + it * 4;   // chunk of 8 d
            const int gt = t0 + ltr;
            const int gd = d0 + c * 8;
            float4 x0 = *(const float4*)&E[(size_t)gt * DIM + gd];
            float4 x1 = *(const float4*)&E[(size_t)gt * DIM + gd + 4];
            float xs[8] = {x0.x, x0.y, x0.z, x0.w, x1.x, x1.y, x1.z, x1.w};
            short8 hv;
#pragma unroll
            for (int j = 0; j < 8; ++j) hv[j] = (short)f16bits(xs[j]);
            *(short8*)&encH[bofs1 + tiled_off(gt, gd, DIM / 32)] = hv;
#pragma unroll
            for (int j = 0; j < 8; ++j) T[c * 8 + j][ltr] = (ushort_t)hv[j];
        }
        __syncthreads();

        const int dr = tid >> 2;           // 0..63 d-row
#pragma unroll
        for (int it = 0; it < 2; ++it) {
            const int tc = (tid & 3) + it * 4;   // chunk of 8 t
            short8 v = *(const short8*)&T[dr][tc * 8];
            *(short8*)&encT[bofs2 + tiled_off(d0 + dr, t0 + tc * 8, TENC / 32)] = v;
        }
    } else {
        const int u0 = (blockIdx.y - 32) * 64;
        const float* D = dec + (size_t)b * TDEC * DIM;
        const size_t bofs = (size_t)b * TDEC * DIM;

        const int lur = tid >> 2;          // 0..63 u-row
#pragma unroll
        for (int it = 0; it < 2; ++it) {
            const int c  = (tid & 3) + it * 4;
            const int gu = u0 + lur;
            const int gd = d0 + c * 8;
            float4 x0 = *(const float4*)&D[(size_t)gu * DIM + gd];
            float4 x1 = *(const float4*)&D[(size_t)gu * DIM + gd + 4];
            float xs[8] = {x0.x, x0.y, x0.z, x0.w, x1.x, x1.y, x1.z, x1.w};
            short8 hv, lv;
#pragma unroll
            for (int j = 0; j < 8; ++j) {
                ushort_t h = f16bits(xs[j]);
                hv[j] = (short)h;
                lv[j] = (short)f16bits(xs[j] - f16val(h));
            }
            const size_t off = bofs + tiled_off(gu, gd, DIM / 32);
            *(short8*)&decH[off] = hv;
            *(short8*)&decL[off] = lv;
        }
    }
}

// ---------------------------------------------------------------------------
// gemm1_lds: p16[b,t,u] = exp(raw - M_tile), fp16; raw = encH*(decH+decL)
// (2 MFMA/pair). XCD-batch affinity (x=batch). Fused full-tile column max,
// exp, and (M_tile, sum) partial stats -> pm/ps (in d_out context region).
// ---------------------------------------------------------------------------
__global__ __launch_bounds__(256) void gemm1_lds(
    const ushort_t* __restrict__ encH, const ushort_t* __restrict__ decH,
    const ushort_t* __restrict__ decL, const int* __restrict__ mask,
    ushort_t* __restrict__ p16, float* __restrict__ pm, float* __restrict__ ps)
{
    __shared__ __align__(16) ushort_t Ah[128 * 32];
    __shared__ __align__(16) ushort_t Bh[128 * 32];
    __shared__ __align__(16) ushort_t Bl[128 * 32];
    __shared__ float smx[4][68];
    __shared__ float ssx[4][68];

    const int b  = blockIdx.x;         // batch -> XCD affinity
    const int m0 = blockIdx.y * 128;   // t
    const int n0 = blockIdx.z * 128;   // u
    const int tid = threadIdx.x;

    const int lane = tid & 63;
    const int w    = tid >> 6;
    const int wm   = (w & 1) * 64;
    const int wn   = (w >> 1) * 64;
    const int lr   = lane & 15;
    const int q    = lane >> 4;
    const int l8   = lane * 8;

    const int fa = wm * 32 + q * 128 + lr * 8;
    const int fb = wn * 32 + q * 128 + lr * 8;

    const ushort_t* AH = encH + (size_t)b * TENC * DIM;
    const ushort_t* BH = decH + (size_t)b * TDEC * DIM;
    const ushort_t* BL = decL + (size_t)b * TDEC * DIM;
    ushort_t* P = p16 + (size_t)b * TENC * TDEC;

    f32x4 acc[4][4] = {};

    for (int k0 = 0; k0 < DIM; k0 += 32) {
        __syncthreads();
#pragma unroll
        for (int q2 = 0; q2 < 2; ++q2) {
            const int rg = w * 2 + q2;
            const size_t tA = ((size_t)((m0 >> 4) + rg) * (DIM / 32) + (k0 >> 5)) * 512 + l8;
            const size_t tB = ((size_t)((n0 >> 4) + rg) * (DIM / 32) + (k0 >> 5)) * 512 + l8;
            GLOAD16(AH + tA, &Ah[rg * 512]);
            GLOAD16(BH + tB, &Bh[rg * 512]);
            GLOAD16(BL + tB, &Bl[rg * 512]);
        }
        __syncthreads();

        short8 ah[4], bh[4], bl[4];
#pragma unroll
        for (int i = 0; i < 4; ++i) {
            ah[i] = *(const short8*)&Ah[fa + i * 512];
            bh[i] = *(const short8*)&Bh[fb + i * 512];
            bl[i] = *(const short8*)&Bl[fb + i * 512];
        }
#pragma unroll
        for (int i = 0; i < 4; ++i)
#pragma unroll
            for (int j = 0; j < 4; ++j) {
                acc[i][j] = __builtin_amdgcn_mfma_f32_16x16x32_f16(ah[i], bh[j], acc[i][j], 0, 0, 0);
                acc[i][j] = __builtin_amdgcn_mfma_f32_16x16x32_f16(ah[i], bl[j], acc[i][j], 0, 0, 0);
            }
    }

    float mkv[4][4];
#pragma unroll
    for (int i = 0; i < 4; ++i)
#pragma unroll
        for (int rr = 0; rr < 4; ++rr) {
            const int t = m0 + wm + i * 16 + q * 4 + rr;
            mkv[i][rr] = (mask[b * TENC + t] == 0) ? NEG_BIG : 0.0f;
        }

    // pass A: per-lane column max
    float cm[4] = {-INFINITY, -INFINITY, -INFINITY, -INFINITY};
#pragma unroll
    for (int i = 0; i < 4; ++i)
#pragma unroll
        for (int rr = 0; rr < 4; ++rr)
#pragma unroll
            for (int j = 0; j < 4; ++j)
                cm[j] = fmaxf(cm[j], acc[i][j][rr] - mkv[i][rr]);
#pragma unroll
    for (int j = 0; j < 4; ++j) {
        cm[j] = fmaxf(cm[j], __shfl_xor(cm[j], 16, 64));
        cm[j] = fmaxf(cm[j], __shfl_xor(cm[j], 32, 64));
    }
    if (q == 0) {
#pragma unroll
        for (int j = 0; j < 4; ++j) smx[w][j * 16 + lr] = cm[j];
    }
    __syncthreads();
    float M[4];
#pragma unroll
    for (int j = 0; j < 4; ++j)
        M[j] = fmaxf(smx[w][j * 16 + lr], smx[w ^ 1][j * 16 + lr]);

    // pass B: p = exp(v - M), write fp16, accumulate sum
    float cs[4] = {0.f, 0.f, 0.f, 0.f};
#pragma unroll
    for (int i = 0; i < 4; ++i)
#pragma unroll
        for (int rr = 0; rr < 4; ++rr) {
            const int t = m0 + wm + i * 16 + q * 4 + rr;
#pragma unroll
            for (int j = 0; j < 4; ++j) {
                const int u = n0 + wn + j * 16 + lr;
                const float p = __expf(acc[i][j][rr] - mkv[i][rr] - M[j]);
                cs[j] += p;
                P[(size_t)t * TDEC + u] = f16bits(p);
            }
        }
#pragma unroll
    for (int j = 0; j < 4; ++j) {
        cs[j] += __shfl_xor(cs[j], 16, 64);
        cs[j] += __shfl_xor(cs[j], 32, 64);
    }
    if (q == 0) {
#pragma unroll
        for (int j = 0; j < 4; ++j) ssx[w][j * 16 + lr] = cs[j];
    }
    __syncthreads();
    if (tid < 128) {
        const int col = tid;
        const int wp  = (col >> 6) * 2;
        const int ci  = col & 63;
        const float Mf = fmaxf(smx[wp][ci], smx[wp + 1][ci]);
        const float Sf = ssx[wp][ci] + ssx[wp + 1][ci];
        const int idx = b * TDEC + n0 + col;
        const int tb  = m0 >> 7;
        pm[(size_t)tb * (BATCH * TDEC) + idx] = Mf;
        ps[(size_t)tb * (BATCH * TDEC) + idx] = Sf;
    }
}

// ---------------------------------------------------------------------------
// norm: exp-free. scores = p16 * w,  w[u] = exp(M_tb - M_global)/S_global.
// Writes scores fp32 (d_out) + scoresT fp16 tiled (rows=u, K=t).
// ---------------------------------------------------------------------------
__global__ __launch_bounds__(256) void norm_kernel(
    const ushort_t* __restrict__ p16, float* __restrict__ scores,
    const float* __restrict__ pm, const float* __restrict__ ps,
    ushort_t* __restrict__ scoresT)
{
    __shared__ ushort_t T[64][72];   // [u][t]
    __shared__ float cW[64];

    const int b  = blockIdx.z;
    const int t0 = blockIdx.x * 64;
    const int u0 = blockIdx.y * 64;
    const int tb = t0 >> 7;
    const int tid = threadIdx.x;

    if (tid < 64) {
        const int idx = b * TDEC + u0 + tid;
        float M = -INFINITY;
#pragma unroll
        for (int z = 0; z < 16; ++z)
            M = fmaxf(M, pm[(size_t)z * (BATCH * TDEC) + idx]);
        float s = 0.0f;
#pragma unroll
        for (int z = 0; z < 16; ++z)
            s += ps[(size_t)z * (BATCH * TDEC) + idx] *
                 __expf(pm[(size_t)z * (BATCH * TDEC) + idx] - M);
        cW[tid] = __expf(pm[(size_t)tb * (BATCH * TDEC) + idx] - M) / s;
    }
    __syncthreads();

    const int tr  = tid >> 4;
    const int ucl = (tid & 15) * 4;

    const float w0 = cW[ucl + 0], w1 = cW[ucl + 1];
    const float w2 = cW[ucl + 2], w3 = cW[ucl + 3];

    const ushort_t* Pb = p16 + (size_t)b * TENC * TDEC;
    float* Sb = scores + (size_t)b * TENC * TDEC;

#pragma unroll
    for (int i = 0; i < 4; ++i) {
        const int t = t0 + tr + 16 * i;
        ushort4 pv = *(const ushort4*)&Pb[(size_t)t * TDEC + u0 + ucl];
        float4 sc;
        sc.x = f16val(pv.x) * w0;
        sc.y = f16val(pv.y) * w1;
        sc.z = f16val(pv.z) * w2;
        sc.w = f16val(pv.w) * w3;
        *(float4*)&Sb[(size_t)t * TDEC + u0 + ucl] = sc;
        const int tloc = tr + 16 * i;
        T[ucl + 0][tloc] = f16bits(sc.x);
        T[ucl + 1][tloc] = f16bits(sc.y);
        T[ucl + 2][tloc] = f16bits(sc.z);
        T[ucl + 3][tloc] = f16bits(sc.w);
    }
    __syncthreads();

    const size_t bofs = (size_t)b * TDEC * TENC;
    const int ur = tid >> 2;
#pragma unroll
    for (int it = 0; it < 2; ++it) {
        const int tc = (tid & 3) + it * 4;
        short8 v = *(const short8*)&T[ur][tc * 8];
        *(short8*)&scoresT[bofs + tiled_off(u0 + ur, t0 + tc * 8, TENC / 32)] = v;
    }
}

// ---------------------------------------------------------------------------
// gemm2_lds: fp16 partial[ks] = scoresT*encT^T k-slice. 128x128 tile
// (r8-proven occupancy: 64 acc VGPRs, 16 KB LDS, 4 blocks/CU), split-K=4,
// XCD-batch affinity. Grid (BATCH, 32, 4): y = ks*8 + d-tile, z = u-tile.
// ---------------------------------------------------------------------------
__global__ __launch_bounds__(256) void gemm2_lds(
    const ushort_t* __restrict__ scoresT, const ushort_t* __restrict__ encT,
    ushort_t* __restrict__ p0, ushort_t* __restrict__ p1,
    ushort_t* __restrict__ p2, ushort_t* __restrict__ p3)
{
    __shared__ __align__(16) ushort_t Ah[128 * 32];
    __shared__ __align__(16) ushort_t Bh[128 * 32];

    const int b  = blockIdx.x;             // batch -> XCD affinity
    const int ks = blockIdx.y >> 3;
    const int n0 = (blockIdx.y & 7) * 128; // d
    const int m0 = blockIdx.z * 128;       // u
    const int tid = threadIdx.x;

    const int lane = tid & 63;
    const int w    = tid >> 6;
    const int wm   = (w & 1) * 64;
    const int wn   = (w >> 1) * 64;
    const int lr   = lane & 15;
    const int q    = lane >> 4;
    const int l8   = lane * 8;

    const int fa = wm * 32 + q * 128 + lr * 8;
    const int fb = wn * 32 + q * 128 + lr * 8;

    const ushort_t* A = scoresT + (size_t)b * TDEC * TENC;
    const ushort_t* B = encT    + (size_t)b * DIM * TENC;
    ushort_t* Psel = ks == 0 ? p0 : (ks == 1 ? p1 : (ks == 2 ? p2 : p3));
    ushort_t* P = Psel + (size_t)b * TDEC * DIM;

    const int kbeg = ks * (TENC / 4);
    const int kend = kbeg + TENC / 4;

    f32x4 acc[4][4] = {};

    for (int k0 = kbeg; k0 < kend; k0 += 32) {
        __syncthreads();
#pragma unroll
        for (int q2 = 0; q2 < 2; ++q2) {
            const int rg = w * 2 + q2;
            const size_t tA = ((size_t)((m0 >> 4) + rg) * (TENC / 32) + (k0 >> 5)) * 512 + l8;
            const size_t tB = ((size_t)((n0 >> 4) + rg) * (TENC / 32) + (k0 >> 5)) * 512 + l8;
            GLOAD16(A + tA, &Ah[rg * 512]);
            GLOAD16(B + tB, &Bh[rg * 512]);
        }
        __syncthreads();

        short8 av[4], bv[4];
#pragma unroll
        for (int i = 0; i < 4; ++i) {
            av[i] = *(const short8*)&Ah[fa + i * 512];
            bv[i] = *(const short8*)&Bh[fb + i * 512];
        }
#pragma unroll
        for (int i = 0; i < 4; ++i)
#pragma unroll
            for (int j = 0; j < 4; ++j)
                acc[i][j] = __builtin_amdgcn_mfma_f32_16x16x32_f16(av[i], bv[j], acc[i][j], 0, 0, 0);
    }

#pragma unroll
    for (int i = 0; i < 4; ++i)
#pragma unroll
        for (int rr = 0; rr < 4; ++rr) {
            const int u = m0 + wm + i * 16 + q * 4 + rr;
#pragma unroll
            for (int j = 0; j < 4; ++j) {
                const int d = n0 + wn + j * 16 + lr;
                P[(size_t)u * DIM + d] = f16bits(acc[i][j][rr]);
            }
        }
}

// ---------------------------------------------------------------------------
// reduce_ctx: context = sum of 4 fp16 partials (fp32 accumulate). Grid 2048.
// ---------------------------------------------------------------------------
__global__ __launch_bounds__(256) void reduce_ctx(
    const ushort_t* __restrict__ p0, const ushort_t* __restrict__ p1,
    const ushort_t* __restrict__ p2, const ushort_t* __restrict__ p3,
    float* __restrict__ ctx)
{
    const size_t i8 = ((size_t)blockIdx.x * 256 + threadIdx.x) * 8;
    short8 a = *(const short8*)(p0 + i8);
    short8 b = *(const short8*)(p1 + i8);
    short8 c = *(const short8*)(p2 + i8);
    short8 d = *(const short8*)(p3 + i8);
    float o[8];
#pragma unroll
    for (int j = 0; j < 8; ++j)
        o[j] = f16val((ushort_t)a[j]) + f16val((ushort_t)b[j])
             + f16val((ushort_t)c[j]) + f16val((ushort_t)d[j]);
    *(float4*)(ctx + i8)     = make_float4(o[0], o[1], o[2], o[3]);
    *(float4*)(ctx + i8 + 4) = make_float4(o[4], o[5], o[6], o[7]);
}

// ===========================================================================
// FALLBACK PATH (round-2 proven kernels; used if workspace is too small)
// ===========================================================================

__device__ __forceinline__ void store8(ushort_t* ph, ushort_t* pl,
                                       float4 x0, float4 x1) {
    float xs[8] = {x0.x, x0.y, x0.z, x0.w, x1.x, x1.y, x1.z, x1.w};
    short8 hv, lv;
#pragma unroll
    for (int i = 0; i < 8; ++i) {
        unsigned int h, l;
        split2(xs[i], h, l);
        hv[i] = (short)h;
        lv[i] = (short)l;
    }
    *(short8*)ph = hv;
    *(short8*)pl = lv;
}

__device__ __forceinline__ void wr4(ushort_t* ph, ushort_t* pl, const float* x) {
    unsigned int h[4], l[4];
#pragma unroll
    for (int i = 0; i < 4; ++i) split2(x[i], h[i], l[i]);
    *(uint2*)ph = make_uint2(h[0] | (h[1] << 16), h[2] | (h[3] << 16));
    *(uint2*)pl = make_uint2(l[0] | (l[1] << 16), l[2] | (l[3] << 16));
}

__device__ __forceinline__ short8 frag8B(const ushort_t* p) {
    union { short8 v; uint2 u[2]; } f;
    f.u[0] = *(const uint2*)p;
    f.u[1] = *(const uint2*)(p + 4);
    return f.v;
}

__global__ __launch_bounds__(256) void gemm1_mfma(
    const float* __restrict__ enc, const float* __restrict__ dec,
    const int* __restrict__ mask, float* __restrict__ raw)
{
    __shared__ __align__(16) ushort_t Ah[128 * 32];
    __shared__ __align__(16) ushort_t Al[128 * 32];
    __shared__ __align__(16) ushort_t Bh[128 * 32];
    __shared__ __align__(16) ushort_t Bl[128 * 32];

    const int b  = blockIdx.z;
    const int m0 = blockIdx.y * 128;
    const int n0 = blockIdx.x * 128;
    const int tid = threadIdx.x;

    const float* A  = enc + (size_t)b * TENC * DIM;
    const float* Bg = dec + (size_t)b * TDEC * DIM;
    float*       C  = raw + (size_t)b * TENC * TDEC;

    const int lane = tid & 63;
    const int wv   = tid >> 6;
    const int wm   = (wv & 1) * 64;
    const int wn   = (wv >> 1) * 64;
    const int lr   = lane & 15;
    const int q    = lane >> 4;

    const int r0 = tid >> 2;
    const int c8 = (tid & 3) * 8;

    f32x4 acc[4][4] = {};

    for (int k0 = 0; k0 < DIM; k0 += 32) {
        const float* pa0 = A  + (size_t)(m0 + r0) * DIM + k0 + c8;
        const float* pa1 = A  + (size_t)(m0 + r0 + 64) * DIM + k0 + c8;
        const float* pb0 = Bg + (size_t)(n0 + r0) * DIM + k0 + c8;
        const float* pb1 = Bg + (size_t)(n0 + r0 + 64) * DIM + k0 + c8;
        float4 a0 = *(const float4*)pa0, a0b = *(const float4*)(pa0 + 4);
        float4 a1 = *(const float4*)pa1, a1b = *(const float4*)(pa1 + 4);
        float4 b0 = *(const float4*)pb0, b0b = *(const float4*)(pb0 + 4);
        float4 b1 = *(const float4*)pb1, b1b = *(const float4*)(pb1 + 4);

        __syncthreads();
        store8(&Ah[r0 * 32 + c8],        &Al[r0 * 32 + c8],        a0, a0b);
        store8(&Ah[(r0 + 64) * 32 + c8], &Al[(r0 + 64) * 32 + c8], a1, a1b);
        store8(&Bh[r0 * 32 + c8],        &Bl[r0 * 32 + c8],        b0, b0b);
        store8(&Bh[(r0 + 64) * 32 + c8], &Bl[(r0 + 64) * 32 + c8], b1, b1b);
        __syncthreads();

        short8 ah[4], al[4], bh[4], bl[4];
#pragma unroll
        for (int i = 0; i < 4; ++i) {
            ah[i] = *(const short8*)&Ah[(wm + i * 16 + lr) * 32 + q * 8];
            al[i] = *(const short8*)&Al[(wm + i * 16 + lr) * 32 + q * 8];
            bh[i] = *(const short8*)&Bh[(wn + i * 16 + lr) * 32 + q * 8];
            bl[i] = *(const short8*)&Bl[(wn + i * 16 + lr) * 32 + q * 8];
        }
#pragma unroll
        for (int i = 0; i < 4; ++i)
#pragma unroll
            for (int j = 0; j < 4; ++j) {
                acc[i][j] = __builtin_amdgcn_mfma_f32_16x16x32_bf16(ah[i], bh[j], acc[i][j], 0, 0, 0);
                acc[i][j] = __builtin_amdgcn_mfma_f32_16x16x32_bf16(ah[i], bl[j], acc[i][j], 0, 0, 0);
                acc[i][j] = __builtin_amdgcn_mfma_f32_16x16x32_bf16(al[i], bh[j], acc[i][j], 0, 0, 0);
            }
    }

#pragma unroll
    for (int i = 0; i < 4; ++i)
#pragma unroll
        for (int rr = 0; rr < 4; ++rr) {
            const int t = m0 + wm + i * 16 + q * 4 + rr;
            const float mk = (mask[b * TENC + t] == 0) ? NEG_BIG : 0.0f;
#pragma unroll
            for (int j = 0; j < 4; ++j) {
                const int u = n0 + wn + j * 16 + lr;
                C[(size_t)t * TDEC + u] = acc[i][j][rr] - mk;
            }
        }
}

__global__ __launch_bounds__(256) void softmax_kernel(float* __restrict__ S)
{
    const int b  = blockIdx.y;
    const int u0 = blockIdx.x * 16;
    const int up = threadIdx.x & 15;
    const int tg = threadIdx.x >> 4;

    float* col = S + (size_t)b * TENC * TDEC + u0;

    float m = -INFINITY, s = 0.0f;
    for (int t = tg; t < TENC; t += 16) {
        float x = col[(size_t)t * TDEC + up];
        float mn = fmaxf(m, x);
        s = s * __expf(m - mn) + __expf(x - mn);
        m = mn;
    }

    __shared__ float sm[16][17];
    __shared__ float ss[16][17];
    sm[tg][up] = m;
    ss[tg][up] = s;
    __syncthreads();

    float M = -INFINITY;
#pragma unroll
    for (int j = 0; j < 16; ++j) M = fmaxf(M, sm[j][up]);
    float sum = 0.0f;
#pragma unroll
    for (int j = 0; j < 16; ++j) sum += ss[j][up] * __expf(sm[j][up] - M);
    const float inv = 1.0f / sum;

    for (int t = tg; t < TENC; t += 16) {
        float x = col[(size_t)t * TDEC + up];
        col[(size_t)t * TDEC + up] = __expf(x - M) * inv;
    }
}

#define G2_LD 36

__global__ __launch_bounds__(256) void gemm2_mfma(
    const float* __restrict__ scores, const float* __restrict__ enc,
    float* __restrict__ context)
{
    __shared__ __align__(16) ushort_t Ah[128 * G2_LD];
    __shared__ __align__(16) ushort_t Al[128 * G2_LD];
    __shared__ __align__(16) ushort_t Bh[128 * G2_LD];
    __shared__ __align__(16) ushort_t Bl[128 * G2_LD];

    const int b  = blockIdx.z;
    const int m0 = blockIdx.y * 128;
    const int n0 = blockIdx.x * 128;
    const int tid = threadIdx.x;

    const float* S = scores + (size_t)b * TENC * TDEC;
    const float* E = enc    + (size_t)b * TENC * DIM;
    float*       C = context + (size_t)b * TDEC * DIM;

    const int lane = tid & 63;
    const int wv   = tid >> 6;
    const int wm   = (wv & 1) * 64;
    const int wn   = (wv >> 1) * 64;
    const int lr   = lane & 15;
    const int q    = lane >> 4;

    const int ul = tid & 127;
    const int th = (tid >> 7) * 16;

    f32x4 acc[4][4] = {};

    for (int k0 = 0; k0 < TENC; k0 += 32) {
        float av[16], bv[16];
#pragma unroll
        for (int i = 0; i < 4; ++i) {
            const int t = k0 + th + i * 4;
#pragma unroll
            for (int j = 0; j < 4; ++j) {
                av[i * 4 + j] = S[(size_t)(t + j) * TDEC + m0 + ul];
                bv[i * 4 + j] = E[(size_t)(t + j) * DIM + n0 + ul];
            }
        }
        __syncthreads();
#pragma unroll
        for (int i = 0; i < 4; ++i) {
            const int tt = th + i * 4;
            wr4(&Ah[ul * G2_LD + tt], &Al[ul * G2_LD + tt], &av[i * 4]);
            wr4(&Bh[ul * G2_LD + tt], &Bl[ul * G2_LD + tt], &bv[i * 4]);
        }
        __syncthreads();

        short8 ah[4], al[4], bh[4], bl[4];
#pragma unroll
        for (int i = 0; i < 4; ++i) {
            ah[i] = frag8B(&Ah[(wm + i * 16 + lr) * G2_LD + q * 8]);
            al[i] = frag8B(&Al[(wm + i * 16 + lr) * G2_LD + q * 8]);
            bh[i] = frag8B(&Bh[(wn + i * 16 + lr) * G2_LD + q * 8]);
            bl[i] = frag8B(&Bl[(wn + i * 16 + lr) * G2_LD + q * 8]);
        }
#pragma unroll
        for (int i = 0; i < 4; ++i)
#pragma unroll
            for (int j = 0; j < 4; ++j) {
                acc[i][j] = __builtin_amdgcn_mfma_f32_16x16x32_bf16(ah[i], bh[j], acc[i][j], 0, 0, 0);
                acc[i][j] = __builtin_amdgcn_mfma_f32_16x16x32_bf16(ah[i], bl[j], acc[i][j], 0, 0, 0);
                acc[i][j] = __builtin_amdgcn_mfma_f32_16x16x32_bf16(al[i], bh[j], acc[i][j], 0, 0, 0);
            }
    }

#pragma unroll
    for (int i = 0; i < 4; ++i)
#pragma unroll
        for (int rr = 0; rr < 4; ++rr) {
            const int u = m0 + wm + i * 16 + q * 4 + rr;
#pragma unroll
            for (int j = 0; j < 4; ++j) {
                const int d = n0 + wn + j * 16 + lr;
                C[(size_t)u * DIM + d] = acc[i][j][rr];
            }
        }
}

// ===========================================================================
extern "C" void kernel_launch(void* const* d_in, const int* in_sizes, int n_in,
                              void* d_out, int out_size, void* d_ws, size_t ws_size,
                              hipStream_t stream)
{
    const float* enc      = (const float*)d_in[0];
    const int*   enc_mask = (const int*)  d_in[1];
    const float* dec      = (const float*)d_in[2];

    float* context = (float*)d_out;                        // B*TDEC*DIM
    float* scores  = context + (size_t)BATCH * TDEC * DIM; // B*TENC*TDEC

    // Workspace layout (bytes), 128 MiB total:
    //   [  0M, 32M)  encH fp16 tiled        (dead after gemm1 -> fp16 partials)
    //   [ 32M, 48M)  p16 (exp(raw-Mtile))   written by gemm1, read by norm
    //   [ 48M, 64M)  spare
    //   [ 64M, 72M)  decH    [ 72M, 80M) decL
    //   [ 80M,112M)  encT fp16 tiled
    //   [112M,128M)  scoresT fp16 tiled
    // pm/ps (512 KB) live in d_out's context region (overwritten last by
    // reduce_ctx).
    const size_t OFF_ENC_H = 0;
    const size_t OFF_P16   = 33554432;
    const size_t OFF_DEC_H = 67108864;
    const size_t OFF_DEC_L = 75497472;
    const size_t OFF_ENC_T = 83886080;
    const size_t OFF_SCO_T = 117440512;
    const size_t WS_NEED   = 134217728;

    if (ws_size >= WS_NEED) {
        char* w = (char*)d_ws;
        ushort_t* encH    = (ushort_t*)(w + OFF_ENC_H);
        ushort_t* p16     = (ushort_t*)(w + OFF_P16);
        ushort_t* decH    = (ushort_t*)(w + OFF_DEC_H);
        ushort_t* decL    = (ushort_t*)(w + OFF_DEC_L);
        ushort_t* encT    = (ushort_t*)(w + OFF_ENC_T);
        ushort_t* scoresT = (ushort_t*)(w + OFF_SCO_T);
        ushort_t* part0   = (ushort_t*)(w + OFF_ENC_H);             // 8 MiB
        ushort_t* part1   = (ushort_t*)(w + OFF_ENC_H + 8388608);
        ushort_t* part2   = (ushort_t*)(w + OFF_ENC_H + 16777216);
        ushort_t* part3   = (ushort_t*)(w + OFF_ENC_H + 25165824);
        float*    pm      = context;                // 256 KB, in d_out
        float*    ps      = context + 65536;        // 256 KB, in d_out

        prep_fused<<<dim3(DIM / 64, 40, BATCH), 256, 0, stream>>>(
            enc, dec, encH, encT, decH, decL);

        gemm1_lds<<<dim3(BATCH, TENC / 128, TDEC / 128), 256, 0, stream>>>(
            encH, decH, decL, enc_mask, p16, pm, ps);

        norm_kernel<<<dim3(TENC / 64, TDEC / 64, BATCH), 256, 0, stream>>>(
            p16, scores, pm, ps, scoresT);

        gemm2_lds<<<dim3(BATCH, 32, TDEC / 128), 256, 0, stream>>>(
            scoresT, encT, part0, part1, part2, part3);

        reduce_ctx<<<2048, 256, 0, stream>>>(part0, part1, part2, part3, context);
    } else {
        gemm1_mfma<<<dim3(TDEC / 128, TENC / 128, BATCH), 256, 0, stream>>>(
            enc, dec, enc_mask, scores);
        softmax_kernel<<<dim3(TDEC / 16, BATCH), 256, 0, stream>>>(scores);
        gemm2_mfma<<<dim3(DIM / 128, TDEC / 128, BATCH), 256, 0, stream>>>(
            scores, enc, context);
    }
}